// Round 1
// baseline (2123.800 us; speedup 1.0000x reference)
//
#include <hip/hip_runtime.h>
#include <hip/hip_bf16.h>

#define NU 19968
#define NI 6144
#define NNODE (NU + NI)
#define EMB 64
#define VD 4096
#define TD 384
#define NNZE 600000
#define LAMB 0.9f
#define CHUNK 1536
#define NCH 4

// ---------- small helpers ----------

__device__ __forceinline__ void topk_insert(float (&cv)[10], int (&ci)[10], float v, int j) {
    if (v <= cv[9]) return;
#pragma unroll
    for (int s = 0; s < 10; ++s) {
        if (v > cv[s]) {
            float tv = cv[s]; cv[s] = v; v = tv;
            int tj = ci[s]; ci[s] = j; j = tj;
        }
    }
}

__device__ __forceinline__ float2 softmax2(const float* mw) {
    float e0 = expf(mw[0]), e1 = expf(mw[1]);
    float inv = 1.0f / (e0 + e1);
    return make_float2(e0 * inv, e1 * inv);
}

// ---------- 1. transform GEMM: C[M][64] += A[M][K] @ W[K][64]  (split-K, atomic) ----------

__global__ __launch_bounds__(256) void gemm_tr(const float* __restrict__ A, const float* __restrict__ W,
                                               float* __restrict__ C, int M, int K, int kps) {
    __shared__ float At[64][64];  // [k][m]
    __shared__ float Wt[64][64];  // [k][n]
    const int t = threadIdx.x;
    const int m0 = blockIdx.x * 64;
    const int k0 = blockIdx.y * kps;
    const int tm = t & 15, tn = t >> 4;
    float acc[4][4] = {};
    for (int kt = k0; kt < k0 + kps; kt += 64) {
        __syncthreads();
        for (int i = t; i < 1024; i += 256) {
            int m = i >> 4, k4 = (i & 15) << 2;
            float4 v = *(const float4*)(A + (size_t)(m0 + m) * K + kt + k4);
            At[k4 + 0][m] = v.x; At[k4 + 1][m] = v.y; At[k4 + 2][m] = v.z; At[k4 + 3][m] = v.w;
        }
        for (int i = t; i < 1024; i += 256) {
            int kk = i >> 4, n4 = (i & 15) << 2;
            *(float4*)&Wt[kk][n4] = *(const float4*)(W + (size_t)(kt + kk) * 64 + n4);
        }
        __syncthreads();
#pragma unroll
        for (int kk = 0; kk < 64; ++kk) {
            float a[4], b[4];
            *(float4*)a = *(const float4*)&At[kk][tm << 2];
            *(float4*)b = *(const float4*)&Wt[kk][tn << 2];
#pragma unroll
            for (int i = 0; i < 4; ++i)
#pragma unroll
                for (int j = 0; j < 4; ++j) acc[i][j] += a[i] * b[j];
        }
    }
#pragma unroll
    for (int i = 0; i < 4; ++i)
#pragma unroll
        for (int j = 0; j < 4; ++j)
            unsafeAtomicAdd(&C[(size_t)(m0 + (tm << 2) + i) * 64 + (tn << 2) + j], acc[i][j]);
}

// ---------- 2. add bias + row-normalize (one wave per row) ----------

__global__ __launch_bounds__(256) void rownorm(const float* __restrict__ C, const float* __restrict__ bias,
                                               float* __restrict__ xn) {
    int row = blockIdx.x * 4 + (threadIdx.x >> 6);
    int lane = threadIdx.x & 63;
    float v = C[(size_t)row * 64 + lane] + bias[lane];
    float ss = v * v;
#pragma unroll
    for (int o = 32; o; o >>= 1) ss += __shfl_xor(ss, o, 64);
    xn[(size_t)row * 64 + lane] = v * (1.0f / sqrtf(ss));
}

// ---------- 3. fused sim + per-row top-10 over a column chunk ----------
// grid (96 rowblocks, NCH chunks, 2 modalities), 256 threads

__global__ __launch_bounds__(256) void sims_topk(const float* __restrict__ xn_img, const float* __restrict__ xn_txt,
                                                 float* __restrict__ tkv, int* __restrict__ tki) {
    const float* xn = (blockIdx.z == 0) ? xn_img : xn_txt;
    const int r0 = blockIdx.x * 64;
    const int c0 = blockIdx.y * CHUNK;
    __shared__ float rowT[64][64];   // [k][r]
    __shared__ float colT[64][64];   // [k][c]
    __shared__ float simb[64][65];   // [r][c], padded
    const int t = threadIdx.x;
    const int tm = t & 15, tn = t >> 4;
    const int rr = t >> 2, sub = t & 3;   // merge mapping: 4 threads per row

    float cv[10]; int ci[10];
#pragma unroll
    for (int s = 0; s < 10; ++s) { cv[s] = -INFINITY; ci[s] = 0; }

    for (int i = t; i < 1024; i += 256) {
        int r = i >> 4, k4 = (i & 15) << 2;
        float4 v = *(const float4*)(xn + (size_t)(r0 + r) * 64 + k4);
        rowT[k4 + 0][r] = v.x; rowT[k4 + 1][r] = v.y; rowT[k4 + 2][r] = v.z; rowT[k4 + 3][r] = v.w;
    }

    for (int tile = 0; tile < CHUNK / 64; ++tile) {
        const int cbase = c0 + tile * 64;
        __syncthreads();   // rowT ready (first iter); simb merge of prev tile done
        for (int i = t; i < 1024; i += 256) {
            int c = i >> 4, k4 = (i & 15) << 2;
            float4 v = *(const float4*)(xn + (size_t)(cbase + c) * 64 + k4);
            colT[k4 + 0][c] = v.x; colT[k4 + 1][c] = v.y; colT[k4 + 2][c] = v.z; colT[k4 + 3][c] = v.w;
        }
        __syncthreads();
        float acc[4][4] = {};
#pragma unroll
        for (int kk = 0; kk < 64; ++kk) {
            float a[4], b[4];
            *(float4*)a = *(const float4*)&rowT[kk][tm << 2];
            *(float4*)b = *(const float4*)&colT[kk][tn << 2];
#pragma unroll
            for (int i = 0; i < 4; ++i)
#pragma unroll
                for (int j = 0; j < 4; ++j) acc[i][j] += a[i] * b[j];
        }
#pragma unroll
        for (int i = 0; i < 4; ++i)
#pragma unroll
            for (int j = 0; j < 4; ++j) simb[(tm << 2) + i][(tn << 2) + j] = acc[i][j];
        __syncthreads();
        // merge this tile's sims into per-thread top-10 (cols ascending per thread)
#pragma unroll
        for (int q = 0; q < 16; ++q) {
            int c = sub * 16 + q;
            topk_insert(cv, ci, simb[rr][c], cbase + c);
        }
    }
    __syncthreads();
    // stash per-thread lists, then 1 thread/row merges 4 lists -> 10
    float* lv = &rowT[0][0];
    int*   li = (int*)&colT[0][0];
#pragma unroll
    for (int s = 0; s < 10; ++s) { lv[(rr * 4 + sub) * 10 + s] = cv[s]; li[(rr * 4 + sub) * 10 + s] = ci[s]; }
    __syncthreads();
    if (t < 64) {
        float fv[10]; int fi[10];
#pragma unroll
        for (int s = 0; s < 10; ++s) { fv[s] = -INFINITY; fi[s] = 0; }
        for (int u = 0; u < 40; ++u) topk_insert(fv, fi, lv[t * 40 + u], li[t * 40 + u]);
        size_t base = ((size_t)(blockIdx.z * NI + r0 + t) * NCH + blockIdx.y) * 10;
#pragma unroll
        for (int s = 0; s < 10; ++s) { tkv[base + s] = fv[s]; tki[base + s] = fi[s]; }
    }
}

// ---------- 4. merge NCH chunk lists -> final top-10 per (modality,row) ----------

__global__ void merge_chunks(const float* __restrict__ tkv, const int* __restrict__ tki,
                             float* __restrict__ fvv, int* __restrict__ fii) {
    int g = blockIdx.x * blockDim.x + threadIdx.x;
    if (g >= 2 * NI) return;
    float cv[10]; int ci[10];
#pragma unroll
    for (int s = 0; s < 10; ++s) { cv[s] = -INFINITY; ci[s] = 0; }
    for (int u = 0; u < NCH * 10; ++u) topk_insert(cv, ci, tkv[(size_t)g * NCH * 10 + u], tki[(size_t)g * NCH * 10 + u]);
#pragma unroll
    for (int s = 0; s < 10; ++s) { fvv[(size_t)g * 10 + s] = cv[s]; fii[(size_t)g * 10 + s] = ci[s]; }
}

// ---------- 5. degree^-1/2 of the combined learned graph ----------

__global__ void calc_dinv(const float* __restrict__ fvv, const float* __restrict__ mw, float* __restrict__ dinv) {
    int i = blockIdx.x * blockDim.x + threadIdx.x;
    if (i >= NI) return;
    float2 w = softmax2(mw);
    float s = 0.f;
    for (int u = 0; u < 10; ++u) s += w.x * fvv[(size_t)i * 10 + u];
    for (int u = 0; u < 10; ++u) s += w.y * fvv[(size_t)(NI + i) * 10 + u];
    dinv[i] = (s > 0.f) ? (1.0f / sqrtf(s)) : 0.f;
}

// ---------- 6. h = item_adj @ item_emb, then row-normalize -> hnorm ----------
// one block per item row; compact nonzeros of 0.9*(w0*imgO + w1*txtO) + 0.1*learned into LDS

__global__ __launch_bounds__(256) void compute_h(const float* __restrict__ img_o, const float* __restrict__ txt_o,
                                                 const float* __restrict__ item_emb,
                                                 const float* __restrict__ fvv, const int* __restrict__ fii,
                                                 const float* __restrict__ dinv, const float* __restrict__ mw,
                                                 float* __restrict__ hnorm) {
    const int i = blockIdx.x;
    const int t = threadIdx.x;
    __shared__ int   sj[64];
    __shared__ float sc[64];
    __shared__ int   scnt;
    __shared__ float part[4][64];
    if (t == 0) scnt = 0;
    __syncthreads();
    float2 w = softmax2(mw);
    const float4* ro = (const float4*)(img_o + (size_t)i * NI);
    const float4* to = (const float4*)(txt_o + (size_t)i * NI);
    for (int u = t; u < NI / 4; u += 256) {
        float4 a = ro[u], b = to[u];
        float c[4] = { w.x * a.x + w.y * b.x, w.x * a.y + w.y * b.y,
                       w.x * a.z + w.y * b.z, w.x * a.w + w.y * b.w };
#pragma unroll
        for (int q = 0; q < 4; ++q)
            if (c[q] != 0.f) { int p = atomicAdd(&scnt, 1); sj[p] = u * 4 + q; sc[p] = LAMB * c[q]; }
    }
    if (t < 20) {
        int m = t / 10, s = t % 10;
        float v = fvv[((size_t)m * NI + i) * 10 + s];
        int   j = fii[((size_t)m * NI + i) * 10 + s];
        float wm = m ? w.y : w.x;
        float c = (1.0f - LAMB) * wm * v * dinv[i] * dinv[j];
        int p = atomicAdd(&scnt, 1); sj[p] = j; sc[p] = c;
    }
    __syncthreads();
    const int cnt = scnt;
    const int dim = t & 63, q = t >> 6;
    float acc = 0.f;
    for (int e = q; e < cnt; e += 4) acc += sc[e] * item_emb[(size_t)sj[e] * 64 + dim];
    part[q][dim] = acc;
    __syncthreads();
    if (t < 64) {
        float h = part[0][t] + part[1][t] + part[2][t] + part[3][t];
        float ss = h * h;
#pragma unroll
        for (int o = 32; o; o >>= 1) ss += __shfl_xor(ss, o, 64);
        float scale = 1.0f / fmaxf(sqrtf(ss), 1e-12f);
        hnorm[(size_t)i * 64 + t] = h * scale;
    }
}

// ---------- 7. one user-item propagation layer: out[src] += val * in[dst] ----------

__global__ __launch_bounds__(256) void ui_layer(const float* __restrict__ uin, const float* __restrict__ iin,
                                                const float* __restrict__ full_in,
                                                const int* __restrict__ aidx, const float* __restrict__ avals,
                                                float* __restrict__ out) {
    int g = blockIdx.x * 256 + threadIdx.x;
    if (g >= NNZE * 16) return;
    int e = g >> 4, q = g & 15;
    int src = aidx[e];
    int dst = aidx[NNZE + e];
    float v = avals[e];
    const float* inrow = full_in ? full_in + (size_t)dst * 64
                                 : (dst < NU ? uin + (size_t)dst * 64 : iin + (size_t)(dst - NU) * 64);
    float4 x = *(const float4*)(inrow + q * 4);
    float* o = out + (size_t)src * 64 + q * 4;
    unsafeAtomicAdd(o + 0, v * x.x);
    unsafeAtomicAdd(o + 1, v * x.y);
    unsafeAtomicAdd(o + 2, v * x.z);
    unsafeAtomicAdd(o + 3, v * x.w);
}

// ---------- 8. final: mean of 3 layers (+ hnorm for items) ----------

__global__ __launch_bounds__(256) void final_out(const float* __restrict__ ue, const float* __restrict__ ie,
                                                 const float* __restrict__ e1, const float* __restrict__ e2,
                                                 const float* __restrict__ hnorm, float* __restrict__ out) {
    int g = blockIdx.x * 256 + threadIdx.x;   // float4 index over NNODE*16
    if (g >= NNODE * 16) return;
    int n = g >> 4;
    float4 a = (n < NU) ? ((const float4*)ue)[g] : ((const float4*)ie)[g - NU * 16];
    float4 b = ((const float4*)e1)[g];
    float4 c = ((const float4*)e2)[g];
    const float third = 1.0f / 3.0f;
    float4 r;
    r.x = (a.x + b.x + c.x) * third;
    r.y = (a.y + b.y + c.y) * third;
    r.z = (a.z + b.z + c.z) * third;
    r.w = (a.w + b.w + c.w) * third;
    if (n >= NU) {
        float4 h = ((const float4*)hnorm)[g - NU * 16];
        r.x += h.x; r.y += h.y; r.z += h.z; r.w += h.w;
    }
    ((float4*)out)[g] = r;
}

// ---------- launch ----------

extern "C" void kernel_launch(void* const* d_in, const int* in_sizes, int n_in,
                              void* d_out, int out_size, void* d_ws, size_t ws_size,
                              hipStream_t stream) {
    const float* user_emb   = (const float*)d_in[0];
    const float* item_emb   = (const float*)d_in[1];
    const float* image_feat = (const float*)d_in[2];
    const float* text_feat  = (const float*)d_in[3];
    const float* img_w      = (const float*)d_in[4];
    const float* img_b      = (const float*)d_in[5];
    const float* txt_w      = (const float*)d_in[6];
    const float* txt_b      = (const float*)d_in[7];
    const float* mw         = (const float*)d_in[8];
    const float* img_orig   = (const float*)d_in[9];
    const float* txt_orig   = (const float*)d_in[10];
    const int*   aidx       = (const int*)d_in[11];
    const float* avals      = (const float*)d_in[12];

    float* ws = (float*)d_ws;
    // workspace layout (float elements)
    float* xn_img = ws;                       // 393216
    float* xn_txt = xn_img + 393216;          // 393216
    float* C_img  = xn_txt + 393216;          // 393216
    float* C_txt  = C_img  + 393216;          // 393216
    float* tk_val = C_txt  + 393216;          // 2*6144*NCH*10 = 491520
    int*   tk_idx = (int*)(tk_val + 491520);  // 491520
    float* fin_val= (float*)(tk_idx + 491520);// 122880
    int*   fin_idx= (int*)(fin_val + 122880); // 122880
    float* dinv   = (float*)(fin_idx + 122880);// 6144
    float* hnorm  = dinv + NI;                // 393216
    float* ego1   = hnorm + 393216;           // 1671168
    float* ego2   = ego1 + 1671168;           // 1671168

    hipMemsetAsync(C_img, 0, (size_t)393216 * 4, stream);
    hipMemsetAsync(C_txt, 0, (size_t)393216 * 4, stream);
    hipMemsetAsync(ego1, 0, (size_t)1671168 * 4, stream);
    hipMemsetAsync(ego2, 0, (size_t)1671168 * 4, stream);

    // 1. transforms
    gemm_tr<<<dim3(NI / 64, 8), 256, 0, stream>>>(image_feat, img_w, C_img, NI, VD, VD / 8);
    gemm_tr<<<dim3(NI / 64, 6), 256, 0, stream>>>(text_feat,  txt_w, C_txt, NI, TD, TD / 6);

    // 2. normalize
    rownorm<<<NI / 4, 256, 0, stream>>>(C_img, img_b, xn_img);
    rownorm<<<NI / 4, 256, 0, stream>>>(C_txt, txt_b, xn_txt);

    // 3. sims + chunked top-10
    sims_topk<<<dim3(NI / 64, NCH, 2), 256, 0, stream>>>(xn_img, xn_txt, tk_val, tk_idx);

    // 4. merge chunks
    merge_chunks<<<(2 * NI + 255) / 256, 256, 0, stream>>>(tk_val, tk_idx, fin_val, fin_idx);

    // 5. degrees
    calc_dinv<<<(NI + 255) / 256, 256, 0, stream>>>(fin_val, mw, dinv);

    // 6. h + normalize
    compute_h<<<NI, 256, 0, stream>>>(img_orig, txt_orig, item_emb, fin_val, fin_idx, dinv, mw, hnorm);

    // 7. two UI propagation layers
    int eg = (NNZE * 16 + 255) / 256;
    ui_layer<<<eg, 256, 0, stream>>>(user_emb, item_emb, nullptr, aidx, avals, ego1);
    ui_layer<<<eg, 256, 0, stream>>>(user_emb, item_emb, ego1,    aidx, avals, ego2);

    // 8. final output
    final_out<<<(NNODE * 16 + 255) / 256, 256, 0, stream>>>(user_emb, item_emb, ego1, ego2, hnorm, (float*)d_out);
}

// Round 3
// 1339.682 us; speedup vs baseline: 1.5853x; 1.5853x over previous
//
#include <hip/hip_runtime.h>
#include <hip/hip_bf16.h>

#define NU 19968
#define NI 6144
#define NNODE (NU + NI)
#define EMB 64
#define VD 4096
#define TD 384
#define NNZE 600000
#define LAMB 0.9f

typedef __attribute__((ext_vector_type(8))) short bf16x8;
typedef __attribute__((ext_vector_type(4))) float f32x4;
#define MFMA16(a, b, c) __builtin_amdgcn_mfma_f32_16x16x32_bf16(a, b, c, 0, 0, 0)

// ---------- helpers ----------

__device__ __forceinline__ void topk_insert(float (&cv)[10], int (&ci)[10], float v, int j) {
    if (v <= cv[9]) return;
#pragma unroll
    for (int s = 0; s < 10; ++s) {
        if (v > cv[s]) {
            float tv = cv[s]; cv[s] = v; v = tv;
            int tj = ci[s]; ci[s] = j; j = tj;
        }
    }
}

__device__ __forceinline__ float2 softmax2(const float* mw) {
    float e0 = expf(mw[0]), e1 = expf(mw[1]);
    float inv = 1.0f / (e0 + e1);
    return make_float2(e0 * inv, e1 * inv);
}

__device__ __forceinline__ unsigned short f2bf(float f) {      // RNE f32->bf16 bits
    unsigned int u = __float_as_uint(f);
    unsigned int r = (u + 0x7FFFu + ((u >> 16) & 1u)) >> 16;
    return (unsigned short)r;
}
__device__ __forceinline__ float bf2f(unsigned short h) { return __uint_as_float(((unsigned int)h) << 16); }

// ---------- 1. transform GEMM: C[M][64] += A[M][K] @ W[K][64]  (split-K, atomic) ----------

__global__ __launch_bounds__(256) void gemm_tr(const float* __restrict__ A, const float* __restrict__ W,
                                               float* __restrict__ C, int M, int K, int kps) {
    __shared__ float At[64][64];
    __shared__ float Wt[64][64];
    const int t = threadIdx.x;
    const int m0 = blockIdx.x * 64;
    const int k0 = blockIdx.y * kps;
    const int tm = t & 15, tn = t >> 4;
    float acc[4][4] = {};
    for (int kt = k0; kt < k0 + kps; kt += 64) {
        __syncthreads();
        for (int i = t; i < 1024; i += 256) {
            int m = i >> 4, k4 = (i & 15) << 2;
            float4 v = *(const float4*)(A + (size_t)(m0 + m) * K + kt + k4);
            At[k4 + 0][m] = v.x; At[k4 + 1][m] = v.y; At[k4 + 2][m] = v.z; At[k4 + 3][m] = v.w;
        }
        for (int i = t; i < 1024; i += 256) {
            int kk = i >> 4, n4 = (i & 15) << 2;
            *(float4*)&Wt[kk][n4] = *(const float4*)(W + (size_t)(kt + kk) * 64 + n4);
        }
        __syncthreads();
#pragma unroll
        for (int kk = 0; kk < 64; ++kk) {
            float a[4], b[4];
            *(float4*)a = *(const float4*)&At[kk][tm << 2];
            *(float4*)b = *(const float4*)&Wt[kk][tn << 2];
#pragma unroll
            for (int i = 0; i < 4; ++i)
#pragma unroll
                for (int j = 0; j < 4; ++j) acc[i][j] += a[i] * b[j];
        }
    }
#pragma unroll
    for (int i = 0; i < 4; ++i)
#pragma unroll
        for (int j = 0; j < 4; ++j)
            unsafeAtomicAdd(&C[(size_t)(m0 + (tm << 2) + i) * 64 + (tn << 2) + j], acc[i][j]);
}

// ---------- 2. bias + row-normalize -> split bf16 (hi, lo) ----------

__global__ __launch_bounds__(256) void rownorm(const float* __restrict__ C, const float* __restrict__ bias,
                                               unsigned short* __restrict__ xh, unsigned short* __restrict__ xl) {
    int row = blockIdx.x * 4 + (threadIdx.x >> 6);
    int lane = threadIdx.x & 63;
    float v = C[(size_t)row * 64 + lane] + bias[lane];
    float ss = v * v;
#pragma unroll
    for (int o = 32; o; o >>= 1) ss += __shfl_xor(ss, o, 64);
    float xn = v * (1.0f / sqrtf(ss));
    unsigned short h = f2bf(xn);
    float lo = xn - bf2f(h);
    xh[(size_t)row * 64 + lane] = h;
    xl[(size_t)row * 64 + lane] = f2bf(lo);
}

// ---------- 3. MFMA sims + per-row top-10 over ALL cols ----------
// grid (96 rowblocks, 2 modalities) x 256 threads; 64 rows/block, full 6144 cols

__global__ __launch_bounds__(256) void sims_topk_mfma(const unsigned short* __restrict__ xh_img,
                                                      const unsigned short* __restrict__ xl_img,
                                                      const unsigned short* __restrict__ xh_txt,
                                                      const unsigned short* __restrict__ xl_txt,
                                                      float* __restrict__ fvv, int* __restrict__ fii) {
    const unsigned short* xh = blockIdx.y ? xh_txt : xh_img;
    const unsigned short* xl = blockIdx.y ? xl_txt : xl_img;
    const int r0 = blockIdx.x * 64;
    const int t = threadIdx.x;
    const int wave = t >> 6, lane = t & 63;
    const int fr = lane & 15, fq = lane >> 4;

    __shared__ float simb[64][65];
    __shared__ float lvs[64 * 40];
    __shared__ int   lis[64 * 40];

    // A fragments: rows of this wave (fixed for whole kernel)
    const size_t abase = (size_t)(r0 + wave * 16 + fr) * 64 + fq * 8;
    bf16x8 ahi0 = *(const bf16x8*)(xh + abase);
    bf16x8 ahi1 = *(const bf16x8*)(xh + abase + 32);
    bf16x8 alo0 = *(const bf16x8*)(xl + abase);
    bf16x8 alo1 = *(const bf16x8*)(xl + abase + 32);

    float cv[10]; int ci[10];
#pragma unroll
    for (int s = 0; s < 10; ++s) { cv[s] = -INFINITY; ci[s] = 0; }
    const int rr = t >> 2, sub = t & 3;

    for (int ct = 0; ct < NI / 64; ++ct) {
        const int cbase = ct * 64;
        f32x4 acc[4];
#pragma unroll
        for (int cs = 0; cs < 4; ++cs) {
            const size_t bbase = (size_t)(cbase + cs * 16 + fr) * 64 + fq * 8;
            bf16x8 bhi0 = *(const bf16x8*)(xh + bbase);
            bf16x8 bhi1 = *(const bf16x8*)(xh + bbase + 32);
            bf16x8 blo0 = *(const bf16x8*)(xl + bbase);
            bf16x8 blo1 = *(const bf16x8*)(xl + bbase + 32);
            f32x4 a = {0.f, 0.f, 0.f, 0.f};
            a = MFMA16(ahi0, bhi0, a);
            a = MFMA16(ahi1, bhi1, a);
            a = MFMA16(ahi0, blo0, a);
            a = MFMA16(ahi1, blo1, a);
            a = MFMA16(alo0, bhi0, a);
            a = MFMA16(alo1, bhi1, a);
            acc[cs] = a;
        }
        __syncthreads();   // previous tile's merge done
#pragma unroll
        for (int cs = 0; cs < 4; ++cs)
#pragma unroll
            for (int r = 0; r < 4; ++r)
                simb[wave * 16 + fq * 4 + r][cs * 16 + fr] = acc[cs][r];
        __syncthreads();
#pragma unroll
        for (int q = 0; q < 16; ++q) {
            int c = sub * 16 + q;
            topk_insert(cv, ci, simb[rr][c], cbase + c);
        }
    }
    // stash per-thread lists, merge 4 lists/row -> 10
#pragma unroll
    for (int s = 0; s < 10; ++s) { lvs[t * 10 + s] = cv[s]; lis[t * 10 + s] = ci[s]; }
    __syncthreads();
    if (t < 64) {
        float fv[10]; int fi[10];
#pragma unroll
        for (int s = 0; s < 10; ++s) { fv[s] = -INFINITY; fi[s] = 0; }
        for (int u = 0; u < 40; ++u) topk_insert(fv, fi, lvs[t * 40 + u], lis[t * 40 + u]);
        size_t base = (size_t)(blockIdx.y * NI + r0 + t) * 10;
#pragma unroll
        for (int s = 0; s < 10; ++s) { fvv[base + s] = fv[s]; fii[base + s] = fi[s]; }
    }
}

// ---------- 4. degree^-1/2 ----------

__global__ void calc_dinv(const float* __restrict__ fvv, const float* __restrict__ mw, float* __restrict__ dinv) {
    int i = blockIdx.x * blockDim.x + threadIdx.x;
    if (i >= NI) return;
    float2 w = softmax2(mw);
    float s = 0.f;
    for (int u = 0; u < 10; ++u) s += w.x * fvv[(size_t)i * 10 + u];
    for (int u = 0; u < 10; ++u) s += w.y * fvv[(size_t)(NI + i) * 10 + u];
    dinv[i] = (s > 0.f) ? (1.0f / sqrtf(s)) : 0.f;
}

// ---------- 5. h = item_adj @ item_emb, row-normalize ----------

__global__ __launch_bounds__(256) void compute_h(const float* __restrict__ img_o, const float* __restrict__ txt_o,
                                                 const float* __restrict__ item_emb,
                                                 const float* __restrict__ fvv, const int* __restrict__ fii,
                                                 const float* __restrict__ dinv, const float* __restrict__ mw,
                                                 float* __restrict__ hnorm) {
    const int i = blockIdx.x;
    const int t = threadIdx.x;
    __shared__ int   sj[64];
    __shared__ float sc[64];
    __shared__ int   scnt;
    __shared__ float part[4][64];
    if (t == 0) scnt = 0;
    __syncthreads();
    float2 w = softmax2(mw);
    const float4* ro = (const float4*)(img_o + (size_t)i * NI);
    const float4* to = (const float4*)(txt_o + (size_t)i * NI);
    for (int u = t; u < NI / 4; u += 256) {
        float4 a = ro[u], b = to[u];
        float c[4] = { w.x * a.x + w.y * b.x, w.x * a.y + w.y * b.y,
                       w.x * a.z + w.y * b.z, w.x * a.w + w.y * b.w };
#pragma unroll
        for (int q = 0; q < 4; ++q)
            if (c[q] != 0.f) { int p = atomicAdd(&scnt, 1); sj[p] = u * 4 + q; sc[p] = LAMB * c[q]; }
    }
    if (t < 20) {
        int m = t / 10, s = t % 10;
        float v = fvv[((size_t)m * NI + i) * 10 + s];
        int   j = fii[((size_t)m * NI + i) * 10 + s];
        float wm = m ? w.y : w.x;
        float c = (1.0f - LAMB) * wm * v * dinv[i] * dinv[j];
        int p = atomicAdd(&scnt, 1); sj[p] = j; sc[p] = c;
    }
    __syncthreads();
    const int cnt = scnt;
    const int dim = t & 63, q = t >> 6;
    float acc = 0.f;
    for (int e = q; e < cnt; e += 4) acc += sc[e] * item_emb[(size_t)sj[e] * 64 + dim];
    part[q][dim] = acc;
    __syncthreads();
    if (t < 64) {
        float h = part[0][t] + part[1][t] + part[2][t] + part[3][t];
        float ss = h * h;
#pragma unroll
        for (int o = 32; o; o >>= 1) ss += __shfl_xor(ss, o, 64);
        float scale = 1.0f / fmaxf(sqrtf(ss), 1e-12f);
        hnorm[(size_t)i * 64 + t] = h * scale;
    }
}

// ---------- 6. CSR build ----------

__global__ void hist_k(const int* __restrict__ aidx, int* __restrict__ cnt) {
    int e = blockIdx.x * 256 + threadIdx.x;
    if (e < NNZE) atomicAdd(&cnt[aidx[e]], 1);
}

__global__ void scan_partial(const int* __restrict__ cnt, int* __restrict__ rp, int* __restrict__ partials) {
    __shared__ int sm[256];
    int t = threadIdx.x;
    int i = blockIdx.x * 256 + t;
    int v = cnt[i];
    sm[t] = v;
    __syncthreads();
    for (int o = 1; o < 256; o <<= 1) {
        int x = (t >= o) ? sm[t - o] : 0;
        __syncthreads();
        sm[t] += x;
        __syncthreads();
    }
    rp[i] = sm[t] - v;                    // exclusive within block
    if (t == 255) partials[blockIdx.x] = sm[255];
}

__global__ void scan_totals(int* __restrict__ partials, int* __restrict__ rp) {
    if (threadIdx.x == 0) {
        int s = 0;
        for (int b = 0; b < NNODE / 256; ++b) { int v = partials[b]; partials[b] = s; s += v; }
        rp[NNODE] = s;
    }
}

__global__ void add_off(int* __restrict__ rp, const int* __restrict__ partials, int* __restrict__ fill) {
    int i = blockIdx.x * 256 + threadIdx.x;
    int v = rp[i] + partials[blockIdx.x];
    rp[i] = v;
    fill[i] = v;
}

__global__ void scatter_k(const int* __restrict__ aidx, const float* __restrict__ avals,
                          int* __restrict__ fill, int* __restrict__ cdst, float* __restrict__ cval) {
    int e = blockIdx.x * 256 + threadIdx.x;
    if (e >= NNZE) return;
    int src = aidx[e];
    int p = atomicAdd(&fill[src], 1);
    cdst[p] = aidx[NNZE + e];
    cval[p] = avals[e];
}

// ---------- 7. gather-based propagation layer (one wave per row) ----------

__global__ __launch_bounds__(256) void ui_gather(const float* __restrict__ uin, const float* __restrict__ iin,
                                                 const float* __restrict__ full_in,
                                                 const int* __restrict__ rp, const int* __restrict__ cdst,
                                                 const float* __restrict__ cval, float* __restrict__ out) {
    int row = blockIdx.x * 4 + (threadIdx.x >> 6);
    int lane = threadIdx.x & 63;
    int s = rp[row], e = rp[row + 1];
    float acc = 0.f;
    int p = s;
    for (; p + 2 <= e; p += 2) {
        int d0 = cdst[p], d1 = cdst[p + 1];
        float v0 = cval[p], v1 = cval[p + 1];
        const float* r0 = full_in ? full_in + (size_t)d0 * 64
                                  : (d0 < NU ? uin + (size_t)d0 * 64 : iin + (size_t)(d0 - NU) * 64);
        const float* r1 = full_in ? full_in + (size_t)d1 * 64
                                  : (d1 < NU ? uin + (size_t)d1 * 64 : iin + (size_t)(d1 - NU) * 64);
        acc += v0 * r0[lane];
        acc += v1 * r1[lane];
    }
    if (p < e) {
        int d0 = cdst[p]; float v0 = cval[p];
        const float* r0 = full_in ? full_in + (size_t)d0 * 64
                                  : (d0 < NU ? uin + (size_t)d0 * 64 : iin + (size_t)(d0 - NU) * 64);
        acc += v0 * r0[lane];
    }
    out[(size_t)row * 64 + lane] = acc;
}

// ---------- 8. final ----------

__global__ __launch_bounds__(256) void final_out(const float* __restrict__ ue, const float* __restrict__ ie,
                                                 const float* __restrict__ e1, const float* __restrict__ e2,
                                                 const float* __restrict__ hnorm, float* __restrict__ out) {
    int g = blockIdx.x * 256 + threadIdx.x;
    if (g >= NNODE * 16) return;
    int n = g >> 4;
    float4 a = (n < NU) ? ((const float4*)ue)[g] : ((const float4*)ie)[g - NU * 16];
    float4 b = ((const float4*)e1)[g];
    float4 c = ((const float4*)e2)[g];
    const float third = 1.0f / 3.0f;
    float4 r;
    r.x = (a.x + b.x + c.x) * third;
    r.y = (a.y + b.y + c.y) * third;
    r.z = (a.z + b.z + c.z) * third;
    r.w = (a.w + b.w + c.w) * third;
    if (n >= NU) {
        float4 h = ((const float4*)hnorm)[g - NU * 16];
        r.x += h.x; r.y += h.y; r.z += h.z; r.w += h.w;
    }
    ((float4*)out)[g] = r;
}

// ---------- launch ----------

extern "C" void kernel_launch(void* const* d_in, const int* in_sizes, int n_in,
                              void* d_out, int out_size, void* d_ws, size_t ws_size,
                              hipStream_t stream) {
    const float* user_emb   = (const float*)d_in[0];
    const float* item_emb   = (const float*)d_in[1];
    const float* image_feat = (const float*)d_in[2];
    const float* text_feat  = (const float*)d_in[3];
    const float* img_w      = (const float*)d_in[4];
    const float* img_b      = (const float*)d_in[5];
    const float* txt_w      = (const float*)d_in[6];
    const float* txt_b      = (const float*)d_in[7];
    const float* mw         = (const float*)d_in[8];
    const float* img_orig   = (const float*)d_in[9];
    const float* txt_orig   = (const float*)d_in[10];
    const int*   aidx       = (const int*)d_in[11];
    const float* avals      = (const float*)d_in[12];

    // workspace layout
    float* C_img = (float*)d_ws;
    float* C_txt = C_img + (size_t)NI * EMB;
    unsigned short* xh_img = (unsigned short*)(C_txt + (size_t)NI * EMB);
    unsigned short* xl_img = xh_img + (size_t)NI * EMB;
    unsigned short* xh_txt = xl_img + (size_t)NI * EMB;
    unsigned short* xl_txt = xh_txt + (size_t)NI * EMB;
    float* fin_val = (float*)(xl_txt + (size_t)NI * EMB);
    int*   fin_idx = (int*)(fin_val + 2 * NI * 10);
    float* dinv    = (float*)(fin_idx + 2 * NI * 10);
    float* hnorm   = dinv + NI;
    float* ego1    = hnorm + (size_t)NI * EMB;
    float* ego2    = ego1 + (size_t)NNODE * EMB;
    int* cnt      = (int*)(ego2 + (size_t)NNODE * EMB);
    int* row_ptr  = cnt + NNODE;
    int* fill     = row_ptr + NNODE + 1;
    int* partials = fill + NNODE;
    int* csr_dst  = partials + 128;
    float* csr_val = (float*)(csr_dst + NNZE);

    hipMemsetAsync(C_img, 0, (size_t)NI * EMB * 4, stream);
    hipMemsetAsync(C_txt, 0, (size_t)NI * EMB * 4, stream);
    hipMemsetAsync(cnt, 0, (size_t)NNODE * 4, stream);

    // CSR build (independent of everything else)
    hist_k<<<(NNZE + 255) / 256, 256, 0, stream>>>(aidx, cnt);
    scan_partial<<<NNODE / 256, 256, 0, stream>>>(cnt, row_ptr, partials);
    scan_totals<<<1, 64, 0, stream>>>(partials, row_ptr);
    add_off<<<NNODE / 256, 256, 0, stream>>>(row_ptr, partials, fill);
    scatter_k<<<(NNZE + 255) / 256, 256, 0, stream>>>(aidx, avals, fill, csr_dst, csr_val);

    // transforms
    gemm_tr<<<dim3(NI / 64, 8), 256, 0, stream>>>(image_feat, img_w, C_img, NI, VD, VD / 8);
    gemm_tr<<<dim3(NI / 64, 6), 256, 0, stream>>>(text_feat,  txt_w, C_txt, NI, TD, TD / 6);

    // normalize + bf16 split
    rownorm<<<NI / 4, 256, 0, stream>>>(C_img, img_b, xh_img, xl_img);
    rownorm<<<NI / 4, 256, 0, stream>>>(C_txt, txt_b, xh_txt, xl_txt);

    // MFMA sims + top-10 (writes final lists directly)
    sims_topk_mfma<<<dim3(NI / 64, 2), 256, 0, stream>>>(xh_img, xl_img, xh_txt, xl_txt, fin_val, fin_idx);

    // degrees
    calc_dinv<<<(NI + 255) / 256, 256, 0, stream>>>(fin_val, mw, dinv);

    // h + normalize
    compute_h<<<NI, 256, 0, stream>>>(img_orig, txt_orig, item_emb, fin_val, fin_idx, dinv, mw, hnorm);

    // two propagation layers via CSR gather
    ui_gather<<<NNODE / 4, 256, 0, stream>>>(user_emb, item_emb, nullptr, row_ptr, csr_dst, csr_val, ego1);
    ui_gather<<<NNODE / 4, 256, 0, stream>>>(user_emb, item_emb, ego1,    row_ptr, csr_dst, csr_val, ego2);

    // final output
    final_out<<<(NNODE * 16 + 255) / 256, 256, 0, stream>>>(user_emb, item_emb, ego1, ego2, hnorm, (float*)d_out);
}

// Round 5
// 1057.774 us; speedup vs baseline: 2.0078x; 1.2665x over previous
//
#include <hip/hip_runtime.h>
#include <hip/hip_bf16.h>

#define NU 19968
#define NI 6144
#define NNODE (NU + NI)
#define EMB 64
#define VD 4096
#define TD 384
#define NNZE 600000
#define LAMB 0.9f
#define NCH 8
#define CPC (NI / NCH)   // 768 cols per chunk

typedef __attribute__((ext_vector_type(8))) short bf16x8;
typedef __attribute__((ext_vector_type(4))) float f32x4;
#define MFMA16(a, b, c) __builtin_amdgcn_mfma_f32_16x16x32_bf16(a, b, c, 0, 0, 0)

// ---------- helpers ----------

__device__ __forceinline__ void topk_insert(float (&cv)[10], int (&ci)[10], float v, int j) {
    if (v <= cv[9]) return;
#pragma unroll
    for (int s = 0; s < 10; ++s) {
        if (v > cv[s]) {
            float tv = cv[s]; cv[s] = v; v = tv;
            int tj = ci[s]; ci[s] = j; j = tj;
        }
    }
}

__device__ __forceinline__ float2 softmax2(const float* mw) {
    float e0 = expf(mw[0]), e1 = expf(mw[1]);
    float inv = 1.0f / (e0 + e1);
    return make_float2(e0 * inv, e1 * inv);
}

__device__ __forceinline__ unsigned short f2bf(float f) {      // RNE f32->bf16 bits
    unsigned int u = __float_as_uint(f);
    unsigned int r = (u + 0x7FFFu + ((u >> 16) & 1u)) >> 16;
    return (unsigned short)r;
}
__device__ __forceinline__ float bf2f(unsigned short h) { return __uint_as_float(((unsigned int)h) << 16); }

// ---------- 1. transform GEMM: C[M][64] += A[M][K] @ W[K][64]  (split-K, atomic) ----------

__global__ __launch_bounds__(256) void gemm_tr(const float* __restrict__ A, const float* __restrict__ W,
                                               float* __restrict__ C, int M, int K, int kps) {
    __shared__ float At[64][64];
    __shared__ float Wt[64][64];
    const int t = threadIdx.x;
    const int m0 = blockIdx.x * 64;
    const int k0 = blockIdx.y * kps;
    const int tm = t & 15, tn = t >> 4;
    float acc[4][4] = {};
    for (int kt = k0; kt < k0 + kps; kt += 64) {
        __syncthreads();
        for (int i = t; i < 1024; i += 256) {
            int m = i >> 4, k4 = (i & 15) << 2;
            float4 v = *(const float4*)(A + (size_t)(m0 + m) * K + kt + k4);
            At[k4 + 0][m] = v.x; At[k4 + 1][m] = v.y; At[k4 + 2][m] = v.z; At[k4 + 3][m] = v.w;
        }
        for (int i = t; i < 1024; i += 256) {
            int kk = i >> 4, n4 = (i & 15) << 2;
            *(float4*)&Wt[kk][n4] = *(const float4*)(W + (size_t)(kt + kk) * 64 + n4);
        }
        __syncthreads();
#pragma unroll
        for (int kk = 0; kk < 64; ++kk) {
            float a[4], b[4];
            *(float4*)a = *(const float4*)&At[kk][tm << 2];
            *(float4*)b = *(const float4*)&Wt[kk][tn << 2];
#pragma unroll
            for (int i = 0; i < 4; ++i)
#pragma unroll
                for (int j = 0; j < 4; ++j) acc[i][j] += a[i] * b[j];
        }
    }
#pragma unroll
    for (int i = 0; i < 4; ++i)
#pragma unroll
        for (int j = 0; j < 4; ++j)
            unsafeAtomicAdd(&C[(size_t)(m0 + (tm << 2) + i) * 64 + (tn << 2) + j], acc[i][j]);
}

// ---------- 2. bias + row-normalize -> split bf16 (hi, lo) ----------

__global__ __launch_bounds__(256) void rownorm(const float* __restrict__ C, const float* __restrict__ bias,
                                               unsigned short* __restrict__ xh, unsigned short* __restrict__ xl) {
    int row = blockIdx.x * 4 + (threadIdx.x >> 6);
    int lane = threadIdx.x & 63;
    float v = C[(size_t)row * 64 + lane] + bias[lane];
    float ss = v * v;
#pragma unroll
    for (int o = 32; o; o >>= 1) ss += __shfl_xor(ss, o, 64);
    float xn = v * (1.0f / sqrtf(ss));
    unsigned short h = f2bf(xn);
    float lo = xn - bf2f(h);
    xh[(size_t)row * 64 + lane] = h;
    xl[(size_t)row * 64 + lane] = f2bf(lo);
}

// ---------- 3. MFMA sims + register top-10, barrier-free ----------
// grid (96 rowblocks, NCH col-chunks, 2 modalities) x 256 threads
// Thread (wave, fq=lane>>4, fr=lane&15) owns rows r0+wave*16+fq*4+{0..3},
// sees cols cbase+cs*16+fr. Top-10 lists live in registers; merge across the
// 16 lanes sharing a row via shfl_xor (masks 1..8 stay inside the 16-lane group).

__global__ __launch_bounds__(256) void sims_topk_mfma(const unsigned short* __restrict__ xh_img,
                                                      const unsigned short* __restrict__ xl_img,
                                                      const unsigned short* __restrict__ xh_txt,
                                                      const unsigned short* __restrict__ xl_txt,
                                                      float* __restrict__ tkv, int* __restrict__ tki) {
    const unsigned short* xh = blockIdx.z ? xh_txt : xh_img;
    const unsigned short* xl = blockIdx.z ? xl_txt : xl_img;
    const int r0 = blockIdx.x * 64;
    const int c0 = blockIdx.y * CPC;
    const int t = threadIdx.x;
    const int wave = t >> 6, lane = t & 63;
    const int fr = lane & 15, fq = lane >> 4;

    // A fragments: rows of this wave (fixed for whole kernel)
    const size_t abase = (size_t)(r0 + wave * 16 + fr) * 64 + fq * 8;
    bf16x8 ahi0 = *(const bf16x8*)(xh + abase);
    bf16x8 ahi1 = *(const bf16x8*)(xh + abase + 32);
    bf16x8 alo0 = *(const bf16x8*)(xl + abase);
    bf16x8 alo1 = *(const bf16x8*)(xl + abase + 32);

    float cv[4][10]; int ci[4][10];
#pragma unroll
    for (int r = 0; r < 4; ++r)
#pragma unroll
        for (int s = 0; s < 10; ++s) { cv[r][s] = -INFINITY; ci[r][s] = 0; }

    for (int ct = 0; ct < CPC / 64; ++ct) {
        const int cbase = c0 + ct * 64;
#pragma unroll
        for (int cs = 0; cs < 4; ++cs) {
            const int c = cbase + cs * 16 + fr;
            const size_t bbase = (size_t)c * 64 + fq * 8;
            bf16x8 bhi0 = *(const bf16x8*)(xh + bbase);
            bf16x8 bhi1 = *(const bf16x8*)(xh + bbase + 32);
            bf16x8 blo0 = *(const bf16x8*)(xl + bbase);
            bf16x8 blo1 = *(const bf16x8*)(xl + bbase + 32);
            f32x4 a = {0.f, 0.f, 0.f, 0.f};
            a = MFMA16(ahi0, bhi0, a);
            a = MFMA16(ahi1, bhi1, a);
            a = MFMA16(ahi0, blo0, a);
            a = MFMA16(ahi1, blo1, a);
            a = MFMA16(alo0, bhi0, a);
            a = MFMA16(alo1, bhi1, a);
            // acc element r corresponds to row r0 + wave*16 + fq*4 + r, col c
#pragma unroll
            for (int r = 0; r < 4; ++r) topk_insert(cv[r], ci[r], a[r], c);
        }
    }

    // merge the 16 per-lane lists of each row (lanes sharing fq) via butterfly
#pragma unroll
    for (int m = 1; m <= 8; m <<= 1) {
#pragma unroll
        for (int r = 0; r < 4; ++r) {
            float ov[10]; int oi[10];
#pragma unroll
            for (int s = 0; s < 10; ++s) {
                ov[s] = __shfl_xor(cv[r][s], m);
                oi[s] = __shfl_xor(ci[r][s], m);
            }
#pragma unroll
            for (int s = 0; s < 10; ++s) topk_insert(cv[r], ci[r], ov[s], oi[s]);
        }
    }

    if (fr == 0) {
#pragma unroll
        for (int r = 0; r < 4; ++r) {
            int row = r0 + wave * 16 + fq * 4 + r;
            size_t base = ((size_t)(blockIdx.z * NI + row) * NCH + blockIdx.y) * 10;
#pragma unroll
            for (int s = 0; s < 10; ++s) { tkv[base + s] = cv[r][s]; tki[base + s] = ci[r][s]; }
        }
    }
}

// ---------- 4. merge NCH chunk lists -> final top-10 per (modality,row) ----------

__global__ void merge_chunks(const float* __restrict__ tkv, const int* __restrict__ tki,
                             float* __restrict__ fvv, int* __restrict__ fii) {
    int g = blockIdx.x * blockDim.x + threadIdx.x;
    if (g >= 2 * NI) return;
    float cv[10]; int ci[10];
#pragma unroll
    for (int s = 0; s < 10; ++s) { cv[s] = -INFINITY; ci[s] = 0; }
    for (int u = 0; u < NCH * 10; ++u) topk_insert(cv, ci, tkv[(size_t)g * NCH * 10 + u], tki[(size_t)g * NCH * 10 + u]);
#pragma unroll
    for (int s = 0; s < 10; ++s) { fvv[(size_t)g * 10 + s] = cv[s]; fii[(size_t)g * 10 + s] = ci[s]; }
}

// ---------- 5. degree^-1/2 ----------

__global__ void calc_dinv(const float* __restrict__ fvv, const float* __restrict__ mw, float* __restrict__ dinv) {
    int i = blockIdx.x * blockDim.x + threadIdx.x;
    if (i >= NI) return;
    float2 w = softmax2(mw);
    float s = 0.f;
    for (int u = 0; u < 10; ++u) s += w.x * fvv[(size_t)i * 10 + u];
    for (int u = 0; u < 10; ++u) s += w.y * fvv[(size_t)(NI + i) * 10 + u];
    dinv[i] = (s > 0.f) ? (1.0f / sqrtf(s)) : 0.f;
}

// ---------- 6. h = item_adj @ item_emb, row-normalize ----------

__global__ __launch_bounds__(256) void compute_h(const float* __restrict__ img_o, const float* __restrict__ txt_o,
                                                 const float* __restrict__ item_emb,
                                                 const float* __restrict__ fvv, const int* __restrict__ fii,
                                                 const float* __restrict__ dinv, const float* __restrict__ mw,
                                                 float* __restrict__ hnorm) {
    const int i = blockIdx.x;
    const int t = threadIdx.x;
    __shared__ int   sj[64];
    __shared__ float sc[64];
    __shared__ int   scnt;
    __shared__ float part[4][64];
    if (t == 0) scnt = 0;
    __syncthreads();
    float2 w = softmax2(mw);
    const float4* ro = (const float4*)(img_o + (size_t)i * NI);
    const float4* to = (const float4*)(txt_o + (size_t)i * NI);
    for (int u = t; u < NI / 4; u += 256) {
        float4 a = ro[u], b = to[u];
        float c[4] = { w.x * a.x + w.y * b.x, w.x * a.y + w.y * b.y,
                       w.x * a.z + w.y * b.z, w.x * a.w + w.y * b.w };
#pragma unroll
        for (int q = 0; q < 4; ++q)
            if (c[q] != 0.f) { int p = atomicAdd(&scnt, 1); sj[p] = u * 4 + q; sc[p] = LAMB * c[q]; }
    }
    if (t < 20) {
        int m = t / 10, s = t % 10;
        float v = fvv[((size_t)m * NI + i) * 10 + s];
        int   j = fii[((size_t)m * NI + i) * 10 + s];
        float wm = m ? w.y : w.x;
        float c = (1.0f - LAMB) * wm * v * dinv[i] * dinv[j];
        int p = atomicAdd(&scnt, 1); sj[p] = j; sc[p] = c;
    }
    __syncthreads();
    const int cnt = scnt;
    const int dim = t & 63, q = t >> 6;
    float acc = 0.f;
    for (int e = q; e < cnt; e += 4) acc += sc[e] * item_emb[(size_t)sj[e] * 64 + dim];
    part[q][dim] = acc;
    __syncthreads();
    if (t < 64) {
        float h = part[0][t] + part[1][t] + part[2][t] + part[3][t];
        float ss = h * h;
#pragma unroll
        for (int o = 32; o; o >>= 1) ss += __shfl_xor(ss, o, 64);
        float scale = 1.0f / fmaxf(sqrtf(ss), 1e-12f);
        hnorm[(size_t)i * 64 + t] = h * scale;
    }
}

// ---------- 7. CSR build ----------

__global__ void hist_k(const int* __restrict__ aidx, int* __restrict__ cnt) {
    int e = blockIdx.x * 256 + threadIdx.x;
    if (e < NNZE) atomicAdd(&cnt[aidx[e]], 1);
}

__global__ void scan_partial(const int* __restrict__ cnt, int* __restrict__ rp, int* __restrict__ partials) {
    __shared__ int sm[256];
    int t = threadIdx.x;
    int i = blockIdx.x * 256 + t;
    int v = cnt[i];
    sm[t] = v;
    __syncthreads();
    for (int o = 1; o < 256; o <<= 1) {
        int x = (t >= o) ? sm[t - o] : 0;
        __syncthreads();
        sm[t] += x;
        __syncthreads();
    }
    rp[i] = sm[t] - v;                    // exclusive within block
    if (t == 255) partials[blockIdx.x] = sm[255];
}

__global__ void scan_totals(int* __restrict__ partials, int* __restrict__ rp) {
    if (threadIdx.x == 0) {
        int s = 0;
        for (int b = 0; b < NNODE / 256; ++b) { int v = partials[b]; partials[b] = s; s += v; }
        rp[NNODE] = s;
    }
}

__global__ void add_off(int* __restrict__ rp, const int* __restrict__ partials, int* __restrict__ fill) {
    int i = blockIdx.x * 256 + threadIdx.x;
    int v = rp[i] + partials[blockIdx.x];
    rp[i] = v;
    fill[i] = v;
}

__global__ void scatter_k(const int* __restrict__ aidx, const float* __restrict__ avals,
                          int* __restrict__ fill, int* __restrict__ cdst, float* __restrict__ cval) {
    int e = blockIdx.x * 256 + threadIdx.x;
    if (e >= NNZE) return;
    int src = aidx[e];
    int p = atomicAdd(&fill[src], 1);
    cdst[p] = aidx[NNZE + e];
    cval[p] = avals[e];
}

// ---------- 8. gather-based propagation layer (one wave per row) ----------

__global__ __launch_bounds__(256) void ui_gather(const float* __restrict__ uin, const float* __restrict__ iin,
                                                 const float* __restrict__ full_in,
                                                 const int* __restrict__ rp, const int* __restrict__ cdst,
                                                 const float* __restrict__ cval, float* __restrict__ out) {
    int row = blockIdx.x * 4 + (threadIdx.x >> 6);
    int lane = threadIdx.x & 63;
    int s = rp[row], e = rp[row + 1];
    float acc = 0.f;
    int p = s;
    for (; p + 2 <= e; p += 2) {
        int d0 = cdst[p], d1 = cdst[p + 1];
        float v0 = cval[p], v1 = cval[p + 1];
        const float* r0 = full_in ? full_in + (size_t)d0 * 64
                                  : (d0 < NU ? uin + (size_t)d0 * 64 : iin + (size_t)(d0 - NU) * 64);
        const float* r1 = full_in ? full_in + (size_t)d1 * 64
                                  : (d1 < NU ? uin + (size_t)d1 * 64 : iin + (size_t)(d1 - NU) * 64);
        acc += v0 * r0[lane];
        acc += v1 * r1[lane];
    }
    if (p < e) {
        int d0 = cdst[p]; float v0 = cval[p];
        const float* r0 = full_in ? full_in + (size_t)d0 * 64
                                  : (d0 < NU ? uin + (size_t)d0 * 64 : iin + (size_t)(d0 - NU) * 64);
        acc += v0 * r0[lane];
    }
    out[(size_t)row * 64 + lane] = acc;
}

// ---------- 9. final ----------

__global__ __launch_bounds__(256) void final_out(const float* __restrict__ ue, const float* __restrict__ ie,
                                                 const float* __restrict__ e1, const float* __restrict__ e2,
                                                 const float* __restrict__ hnorm, float* __restrict__ out) {
    int g = blockIdx.x * 256 + threadIdx.x;
    if (g >= NNODE * 16) return;
    int n = g >> 4;
    float4 a = (n < NU) ? ((const float4*)ue)[g] : ((const float4*)ie)[g - NU * 16];
    float4 b = ((const float4*)e1)[g];
    float4 c = ((const float4*)e2)[g];
    const float third = 1.0f / 3.0f;
    float4 r;
    r.x = (a.x + b.x + c.x) * third;
    r.y = (a.y + b.y + c.y) * third;
    r.z = (a.z + b.z + c.z) * third;
    r.w = (a.w + b.w + c.w) * third;
    if (n >= NU) {
        float4 h = ((const float4*)hnorm)[g - NU * 16];
        r.x += h.x; r.y += h.y; r.z += h.z; r.w += h.w;
    }
    ((float4*)out)[g] = r;
}

// ---------- launch ----------

extern "C" void kernel_launch(void* const* d_in, const int* in_sizes, int n_in,
                              void* d_out, int out_size, void* d_ws, size_t ws_size,
                              hipStream_t stream) {
    const float* user_emb   = (const float*)d_in[0];
    const float* item_emb   = (const float*)d_in[1];
    const float* image_feat = (const float*)d_in[2];
    const float* text_feat  = (const float*)d_in[3];
    const float* img_w      = (const float*)d_in[4];
    const float* img_b      = (const float*)d_in[5];
    const float* txt_w      = (const float*)d_in[6];
    const float* txt_b      = (const float*)d_in[7];
    const float* mw         = (const float*)d_in[8];
    const float* img_orig   = (const float*)d_in[9];
    const float* txt_orig   = (const float*)d_in[10];
    const int*   aidx       = (const int*)d_in[11];
    const float* avals      = (const float*)d_in[12];

    // workspace layout (float elements)
    float* C_img = (float*)d_ws;
    float* C_txt = C_img + (size_t)NI * EMB;
    unsigned short* xh_img = (unsigned short*)(C_txt + (size_t)NI * EMB);
    unsigned short* xl_img = xh_img + (size_t)NI * EMB;
    unsigned short* xh_txt = xl_img + (size_t)NI * EMB;
    unsigned short* xl_txt = xh_txt + (size_t)NI * EMB;
    float* tk_val  = (float*)(xl_txt + (size_t)NI * EMB);       // 2*NI*NCH*10
    int*   tk_idx  = (int*)(tk_val + (size_t)2 * NI * NCH * 10);
    float* fin_val = (float*)(tk_idx + (size_t)2 * NI * NCH * 10);
    int*   fin_idx = (int*)(fin_val + 2 * NI * 10);
    float* dinv    = (float*)(fin_idx + 2 * NI * 10);
    float* hnorm   = dinv + NI;
    float* ego1    = hnorm + (size_t)NI * EMB;
    float* ego2    = ego1 + (size_t)NNODE * EMB;
    int* cnt      = (int*)(ego2 + (size_t)NNODE * EMB);
    int* row_ptr  = cnt + NNODE;
    int* fill     = row_ptr + NNODE + 1;
    int* partials = fill + NNODE;
    int* csr_dst  = partials + 128;
    float* csr_val = (float*)(csr_dst + NNZE);

    hipMemsetAsync(C_img, 0, (size_t)NI * EMB * 4, stream);
    hipMemsetAsync(C_txt, 0, (size_t)NI * EMB * 4, stream);
    hipMemsetAsync(cnt, 0, (size_t)NNODE * 4, stream);

    // CSR build (independent of everything else)
    hist_k<<<(NNZE + 255) / 256, 256, 0, stream>>>(aidx, cnt);
    scan_partial<<<NNODE / 256, 256, 0, stream>>>(cnt, row_ptr, partials);
    scan_totals<<<1, 64, 0, stream>>>(partials, row_ptr);
    add_off<<<NNODE / 256, 256, 0, stream>>>(row_ptr, partials, fill);
    scatter_k<<<(NNZE + 255) / 256, 256, 0, stream>>>(aidx, avals, fill, csr_dst, csr_val);

    // transforms
    gemm_tr<<<dim3(NI / 64, 8), 256, 0, stream>>>(image_feat, img_w, C_img, NI, VD, VD / 8);
    gemm_tr<<<dim3(NI / 64, 6), 256, 0, stream>>>(text_feat,  txt_w, C_txt, NI, TD, TD / 6);

    // normalize + bf16 split
    rownorm<<<NI / 4, 256, 0, stream>>>(C_img, img_b, xh_img, xl_img);
    rownorm<<<NI / 4, 256, 0, stream>>>(C_txt, txt_b, xh_txt, xl_txt);

    // MFMA sims + chunked register top-10
    sims_topk_mfma<<<dim3(NI / 64, NCH, 2), 256, 0, stream>>>(xh_img, xl_img, xh_txt, xl_txt, tk_val, tk_idx);

    // merge chunk lists
    merge_chunks<<<(2 * NI + 255) / 256, 256, 0, stream>>>(tk_val, tk_idx, fin_val, fin_idx);

    // degrees
    calc_dinv<<<(NI + 255) / 256, 256, 0, stream>>>(fin_val, mw, dinv);

    // h + normalize
    compute_h<<<NI, 256, 0, stream>>>(img_orig, txt_orig, item_emb, fin_val, fin_idx, dinv, mw, hnorm);

    // two propagation layers via CSR gather
    ui_gather<<<NNODE / 4, 256, 0, stream>>>(user_emb, item_emb, nullptr, row_ptr, csr_dst, csr_val, ego1);
    ui_gather<<<NNODE / 4, 256, 0, stream>>>(user_emb, item_emb, ego1,    row_ptr, csr_dst, csr_val, ego2);

    // final output
    final_out<<<(NNODE * 16 + 255) / 256, 256, 0, stream>>>(user_emb, item_emb, ego1, ego2, hnorm, (float*)d_out);
}

// Round 6
// 1034.230 us; speedup vs baseline: 2.0535x; 1.0228x over previous
//
#include <hip/hip_runtime.h>
#include <hip/hip_bf16.h>

#define NU 19968
#define NI 6144
#define NNODE (NU + NI)
#define EMB 64
#define VD 4096
#define TD 384
#define NNZE 600000
#define LAMB 0.9f
#define NCH 8
#define CPC (NI / NCH)   // 768 cols per chunk
#define MAXC 16          // candidate cap per row

typedef __attribute__((ext_vector_type(8))) short bf16x8;
typedef __attribute__((ext_vector_type(4))) float f32x4;
#define MFMA16(a, b, c) __builtin_amdgcn_mfma_f32_16x16x32_bf16(a, b, c, 0, 0, 0)

// ---------- helpers ----------

// values-only sorted-insert: 2 ops/step, no branches inside
__device__ __forceinline__ void vins(float (&cv)[10], float v) {
#pragma unroll
    for (int s = 0; s < 10; ++s) {
        float mx = fmaxf(cv[s], v);
        v = fminf(cv[s], v);
        cv[s] = mx;
    }
}

// (value desc, col asc) tie-break insert — matches lax.top_k stability
__device__ __forceinline__ void topk_ins_tie(float (&cv)[10], int (&ci)[10], float v, int j) {
#pragma unroll
    for (int s = 0; s < 10; ++s) {
        bool take = (v > cv[s]) || (v == cv[s] && j < ci[s]);
        if (take) {
            float tv = cv[s]; cv[s] = v; v = tv;
            int tj = ci[s]; ci[s] = j; j = tj;
        }
    }
}

__device__ __forceinline__ float2 softmax2(const float* mw) {
    float e0 = expf(mw[0]), e1 = expf(mw[1]);
    float inv = 1.0f / (e0 + e1);
    return make_float2(e0 * inv, e1 * inv);
}

__device__ __forceinline__ unsigned short f2bf(float f) {      // RNE f32->bf16 bits
    unsigned int u = __float_as_uint(f);
    unsigned int r = (u + 0x7FFFu + ((u >> 16) & 1u)) >> 16;
    return (unsigned short)r;
}
__device__ __forceinline__ float bf2f(unsigned short h) { return __uint_as_float(((unsigned int)h) << 16); }

// shared sim-tile evaluator — MUST be bit-identical between pass A and pass B:
// the 6-MFMA chain is dependency-ordered so results are deterministic.
__device__ __forceinline__ f32x4 sim_tile(const unsigned short* __restrict__ xh,
                                          const unsigned short* __restrict__ xl,
                                          bf16x8 ahi0, bf16x8 ahi1, bf16x8 alo0, bf16x8 alo1,
                                          int c, int fq) {
    const size_t bbase = (size_t)c * 64 + fq * 8;
    bf16x8 bhi0 = *(const bf16x8*)(xh + bbase);
    bf16x8 bhi1 = *(const bf16x8*)(xh + bbase + 32);
    bf16x8 blo0 = *(const bf16x8*)(xl + bbase);
    bf16x8 blo1 = *(const bf16x8*)(xl + bbase + 32);
    f32x4 a = {0.f, 0.f, 0.f, 0.f};
    a = MFMA16(ahi0, bhi0, a);
    a = MFMA16(ahi1, bhi1, a);
    a = MFMA16(ahi0, blo0, a);
    a = MFMA16(ahi1, blo1, a);
    a = MFMA16(alo0, bhi0, a);
    a = MFMA16(alo1, bhi1, a);
    return a;
}

// ---------- 1. transform GEMM: C[M][64] += A[M][K] @ W[K][64]  (split-K, atomic) ----------

__global__ __launch_bounds__(256) void gemm_tr(const float* __restrict__ A, const float* __restrict__ W,
                                               float* __restrict__ C, int M, int K, int kps) {
    __shared__ float At[64][64];
    __shared__ float Wt[64][64];
    const int t = threadIdx.x;
    const int m0 = blockIdx.x * 64;
    const int k0 = blockIdx.y * kps;
    const int tm = t & 15, tn = t >> 4;
    float acc[4][4] = {};
    for (int kt = k0; kt < k0 + kps; kt += 64) {
        __syncthreads();
        for (int i = t; i < 1024; i += 256) {
            int m = i >> 4, k4 = (i & 15) << 2;
            float4 v = *(const float4*)(A + (size_t)(m0 + m) * K + kt + k4);
            At[k4 + 0][m] = v.x; At[k4 + 1][m] = v.y; At[k4 + 2][m] = v.z; At[k4 + 3][m] = v.w;
        }
        for (int i = t; i < 1024; i += 256) {
            int kk = i >> 4, n4 = (i & 15) << 2;
            *(float4*)&Wt[kk][n4] = *(const float4*)(W + (size_t)(kt + kk) * 64 + n4);
        }
        __syncthreads();
#pragma unroll
        for (int kk = 0; kk < 64; ++kk) {
            float a[4], b[4];
            *(float4*)a = *(const float4*)&At[kk][tm << 2];
            *(float4*)b = *(const float4*)&Wt[kk][tn << 2];
#pragma unroll
            for (int i = 0; i < 4; ++i)
#pragma unroll
                for (int j = 0; j < 4; ++j) acc[i][j] += a[i] * b[j];
        }
    }
#pragma unroll
    for (int i = 0; i < 4; ++i)
#pragma unroll
        for (int j = 0; j < 4; ++j)
            unsafeAtomicAdd(&C[(size_t)(m0 + (tm << 2) + i) * 64 + (tn << 2) + j], acc[i][j]);
}

// ---------- 2. bias + row-normalize -> split bf16 (hi, lo) ----------

__global__ __launch_bounds__(256) void rownorm(const float* __restrict__ C, const float* __restrict__ bias,
                                               unsigned short* __restrict__ xh, unsigned short* __restrict__ xl) {
    int row = blockIdx.x * 4 + (threadIdx.x >> 6);
    int lane = threadIdx.x & 63;
    float v = C[(size_t)row * 64 + lane] + bias[lane];
    float ss = v * v;
#pragma unroll
    for (int o = 32; o; o >>= 1) ss += __shfl_xor(ss, o, 64);
    float xn = v * (1.0f / sqrtf(ss));
    unsigned short h = f2bf(xn);
    float lo = xn - bf2f(h);
    xh[(size_t)row * 64 + lane] = h;
    xl[(size_t)row * 64 + lane] = f2bf(lo);
}

// ---------- 3a. Pass A: per-(row,chunk) top-10 VALUES (no indices) ----------
// grid (96 rowblocks, NCH col-chunks, 2 modalities) x 256 threads

__global__ __launch_bounds__(256) void sims_tauA(const unsigned short* __restrict__ xh_img,
                                                 const unsigned short* __restrict__ xl_img,
                                                 const unsigned short* __restrict__ xh_txt,
                                                 const unsigned short* __restrict__ xl_txt,
                                                 float* __restrict__ tkv) {
    const unsigned short* xh = blockIdx.z ? xh_txt : xh_img;
    const unsigned short* xl = blockIdx.z ? xl_txt : xl_img;
    const int r0 = blockIdx.x * 64;
    const int c0 = blockIdx.y * CPC;
    const int t = threadIdx.x;
    const int wave = t >> 6, lane = t & 63;
    const int fr = lane & 15, fq = lane >> 4;

    const size_t abase = (size_t)(r0 + wave * 16 + fr) * 64 + fq * 8;
    bf16x8 ahi0 = *(const bf16x8*)(xh + abase);
    bf16x8 ahi1 = *(const bf16x8*)(xh + abase + 32);
    bf16x8 alo0 = *(const bf16x8*)(xl + abase);
    bf16x8 alo1 = *(const bf16x8*)(xl + abase + 32);

    float cv[4][10];
#pragma unroll
    for (int r = 0; r < 4; ++r)
#pragma unroll
        for (int s = 0; s < 10; ++s) cv[r][s] = -INFINITY;

    for (int ct = 0; ct < CPC / 64; ++ct) {
        const int cbase = c0 + ct * 64;
#pragma unroll
        for (int cs = 0; cs < 4; ++cs) {
            f32x4 a = sim_tile(xh, xl, ahi0, ahi1, alo0, alo1, cbase + cs * 16 + fr, fq);
#pragma unroll
            for (int r = 0; r < 4; ++r)
                if (a[r] > cv[r][9]) vins(cv[r], a[r]);
        }
    }

    // butterfly merge of the 16 lane-lists per row (masks stay inside 16-lane group)
#pragma unroll
    for (int m = 1; m <= 8; m <<= 1) {
#pragma unroll
        for (int r = 0; r < 4; ++r) {
            float ov[10];
#pragma unroll
            for (int s = 0; s < 10; ++s) ov[s] = __shfl_xor(cv[r][s], m);
            bool done = false;
#pragma unroll
            for (int s = 0; s < 10; ++s) {
                if (!done) {
                    if (__all(ov[s] <= cv[r][9])) done = true;   // ov sorted desc, cv[9] only grows
                    else if (ov[s] > cv[r][9]) vins(cv[r], ov[s]);
                }
            }
        }
    }

    if (fr == 0) {
#pragma unroll
        for (int r = 0; r < 4; ++r) {
            int row = r0 + wave * 16 + fq * 4 + r;
            size_t base = ((size_t)(blockIdx.z * NI + row) * NCH + blockIdx.y) * 10;
#pragma unroll
            for (int s = 0; s < 10; ++s) tkv[base + s] = cv[r][s];
        }
    }
}

// ---------- 3b. merge chunk value-lists -> exact per-row 10th-largest (tau) ----------

__global__ void tau_merge(const float* __restrict__ tkv, float* __restrict__ tau) {
    int g = blockIdx.x * blockDim.x + threadIdx.x;
    if (g >= 2 * NI) return;
    float cv[10];
#pragma unroll
    for (int s = 0; s < 10; ++s) cv[s] = -INFINITY;
    for (int u = 0; u < NCH * 10; ++u) {
        float v = tkv[(size_t)g * NCH * 10 + u];
        if (v > cv[9]) vins(cv, v);
    }
    tau[g] = cv[9];
}

// ---------- 3c. Pass B: recompute sims, collect cols with v >= tau ----------

__global__ __launch_bounds__(256) void sims_collect(const unsigned short* __restrict__ xh_img,
                                                    const unsigned short* __restrict__ xl_img,
                                                    const unsigned short* __restrict__ xh_txt,
                                                    const unsigned short* __restrict__ xl_txt,
                                                    const float* __restrict__ tau,
                                                    int* __restrict__ ccnt,
                                                    float* __restrict__ cval, int* __restrict__ ccol) {
    const unsigned short* xh = blockIdx.z ? xh_txt : xh_img;
    const unsigned short* xl = blockIdx.z ? xl_txt : xl_img;
    const int r0 = blockIdx.x * 64;
    const int c0 = blockIdx.y * CPC;
    const int t = threadIdx.x;
    const int wave = t >> 6, lane = t & 63;
    const int fr = lane & 15, fq = lane >> 4;

    const size_t abase = (size_t)(r0 + wave * 16 + fr) * 64 + fq * 8;
    bf16x8 ahi0 = *(const bf16x8*)(xh + abase);
    bf16x8 ahi1 = *(const bf16x8*)(xh + abase + 32);
    bf16x8 alo0 = *(const bf16x8*)(xl + abase);
    bf16x8 alo1 = *(const bf16x8*)(xl + abase + 32);

    float tv[4];
    int grow[4];
#pragma unroll
    for (int r = 0; r < 4; ++r) {
        grow[r] = blockIdx.z * NI + r0 + wave * 16 + fq * 4 + r;
        tv[r] = tau[grow[r]];
    }

    for (int ct = 0; ct < CPC / 64; ++ct) {
        const int cbase = c0 + ct * 64;
#pragma unroll
        for (int cs = 0; cs < 4; ++cs) {
            const int c = cbase + cs * 16 + fr;
            f32x4 a = sim_tile(xh, xl, ahi0, ahi1, alo0, alo1, c, fq);
#pragma unroll
            for (int r = 0; r < 4; ++r) {
                if (a[r] >= tv[r]) {                       // rare: ~10 hits/row total
                    int p = atomicAdd(&ccnt[grow[r]], 1);
                    if (p < MAXC) {
                        cval[(size_t)grow[r] * MAXC + p] = a[r];
                        ccol[(size_t)grow[r] * MAXC + p] = c;
                    }
                }
            }
        }
    }
}

// ---------- 3d. final exact top-10 from candidates (tie-break = lowest col) ----------

__global__ void topk_cand(const int* __restrict__ ccnt, const float* __restrict__ cval,
                          const int* __restrict__ ccol,
                          float* __restrict__ fvv, int* __restrict__ fii) {
    int g = blockIdx.x * blockDim.x + threadIdx.x;
    if (g >= 2 * NI) return;
    float cv[10]; int ci[10];
#pragma unroll
    for (int s = 0; s < 10; ++s) { cv[s] = -INFINITY; ci[s] = 0x7fffffff; }
    int n = ccnt[g]; if (n > MAXC) n = MAXC;
    for (int u = 0; u < n; ++u)
        topk_ins_tie(cv, ci, cval[(size_t)g * MAXC + u], ccol[(size_t)g * MAXC + u]);
#pragma unroll
    for (int s = 0; s < 10; ++s) { fvv[(size_t)g * 10 + s] = cv[s]; fii[(size_t)g * 10 + s] = ci[s]; }
}

// ---------- 4. degree^-1/2 ----------

__global__ void calc_dinv(const float* __restrict__ fvv, const float* __restrict__ mw, float* __restrict__ dinv) {
    int i = blockIdx.x * blockDim.x + threadIdx.x;
    if (i >= NI) return;
    float2 w = softmax2(mw);
    float s = 0.f;
    for (int u = 0; u < 10; ++u) s += w.x * fvv[(size_t)i * 10 + u];
    for (int u = 0; u < 10; ++u) s += w.y * fvv[(size_t)(NI + i) * 10 + u];
    dinv[i] = (s > 0.f) ? (1.0f / sqrtf(s)) : 0.f;
}

// ---------- 5. h = item_adj @ item_emb, row-normalize ----------

__global__ __launch_bounds__(256) void compute_h(const float* __restrict__ img_o, const float* __restrict__ txt_o,
                                                 const float* __restrict__ item_emb,
                                                 const float* __restrict__ fvv, const int* __restrict__ fii,
                                                 const float* __restrict__ dinv, const float* __restrict__ mw,
                                                 float* __restrict__ hnorm) {
    const int i = blockIdx.x;
    const int t = threadIdx.x;
    __shared__ int   sj[64];
    __shared__ float sc[64];
    __shared__ int   scnt;
    __shared__ float part[4][64];
    if (t == 0) scnt = 0;
    __syncthreads();
    float2 w = softmax2(mw);
    const float4* ro = (const float4*)(img_o + (size_t)i * NI);
    const float4* to = (const float4*)(txt_o + (size_t)i * NI);
    for (int u = t; u < NI / 4; u += 256) {
        float4 a = ro[u], b = to[u];
        float c[4] = { w.x * a.x + w.y * b.x, w.x * a.y + w.y * b.y,
                       w.x * a.z + w.y * b.z, w.x * a.w + w.y * b.w };
#pragma unroll
        for (int q = 0; q < 4; ++q)
            if (c[q] != 0.f) { int p = atomicAdd(&scnt, 1); sj[p] = u * 4 + q; sc[p] = LAMB * c[q]; }
    }
    if (t < 20) {
        int m = t / 10, s = t % 10;
        float v = fvv[((size_t)m * NI + i) * 10 + s];
        int   j = fii[((size_t)m * NI + i) * 10 + s];
        float wm = m ? w.y : w.x;
        float c = (1.0f - LAMB) * wm * v * dinv[i] * dinv[j];
        int p = atomicAdd(&scnt, 1); sj[p] = j; sc[p] = c;
    }
    __syncthreads();
    const int cnt = scnt;
    const int dim = t & 63, q = t >> 6;
    float acc = 0.f;
    for (int e = q; e < cnt; e += 4) acc += sc[e] * item_emb[(size_t)sj[e] * 64 + dim];
    part[q][dim] = acc;
    __syncthreads();
    if (t < 64) {
        float h = part[0][t] + part[1][t] + part[2][t] + part[3][t];
        float ss = h * h;
#pragma unroll
        for (int o = 32; o; o >>= 1) ss += __shfl_xor(ss, o, 64);
        float scale = 1.0f / fmaxf(sqrtf(ss), 1e-12f);
        hnorm[(size_t)i * 64 + t] = h * scale;
    }
}

// ---------- 6. CSR build ----------

__global__ void hist_k(const int* __restrict__ aidx, int* __restrict__ cnt) {
    int e = blockIdx.x * 256 + threadIdx.x;
    if (e < NNZE) atomicAdd(&cnt[aidx[e]], 1);
}

__global__ void scan_partial(const int* __restrict__ cnt, int* __restrict__ rp, int* __restrict__ partials) {
    __shared__ int sm[256];
    int t = threadIdx.x;
    int i = blockIdx.x * 256 + t;
    int v = cnt[i];
    sm[t] = v;
    __syncthreads();
    for (int o = 1; o < 256; o <<= 1) {
        int x = (t >= o) ? sm[t - o] : 0;
        __syncthreads();
        sm[t] += x;
        __syncthreads();
    }
    rp[i] = sm[t] - v;                    // exclusive within block
    if (t == 255) partials[blockIdx.x] = sm[255];
}

__global__ void scan_totals(int* __restrict__ partials, int* __restrict__ rp) {
    if (threadIdx.x == 0) {
        int s = 0;
        for (int b = 0; b < NNODE / 256; ++b) { int v = partials[b]; partials[b] = s; s += v; }
        rp[NNODE] = s;
    }
}

__global__ void add_off(int* __restrict__ rp, const int* __restrict__ partials, int* __restrict__ fill) {
    int i = blockIdx.x * 256 + threadIdx.x;
    int v = rp[i] + partials[blockIdx.x];
    rp[i] = v;
    fill[i] = v;
}

__global__ void scatter_k(const int* __restrict__ aidx, const float* __restrict__ avals,
                          int* __restrict__ fill, int* __restrict__ cdst, float* __restrict__ cval) {
    int e = blockIdx.x * 256 + threadIdx.x;
    if (e >= NNZE) return;
    int src = aidx[e];
    int p = atomicAdd(&fill[src], 1);
    cdst[p] = aidx[NNZE + e];
    cval[p] = avals[e];
}

// ---------- 7. gather-based propagation layer (one wave per row) ----------

__global__ __launch_bounds__(256) void ui_gather(const float* __restrict__ uin, const float* __restrict__ iin,
                                                 const float* __restrict__ full_in,
                                                 const int* __restrict__ rp, const int* __restrict__ cdst,
                                                 const float* __restrict__ cval, float* __restrict__ out) {
    int row = blockIdx.x * 4 + (threadIdx.x >> 6);
    int lane = threadIdx.x & 63;
    int s = rp[row], e = rp[row + 1];
    float acc = 0.f;
    int p = s;
    for (; p + 2 <= e; p += 2) {
        int d0 = cdst[p], d1 = cdst[p + 1];
        float v0 = cval[p], v1 = cval[p + 1];
        const float* r0 = full_in ? full_in + (size_t)d0 * 64
                                  : (d0 < NU ? uin + (size_t)d0 * 64 : iin + (size_t)(d0 - NU) * 64);
        const float* r1 = full_in ? full_in + (size_t)d1 * 64
                                  : (d1 < NU ? uin + (size_t)d1 * 64 : iin + (size_t)(d1 - NU) * 64);
        acc += v0 * r0[lane];
        acc += v1 * r1[lane];
    }
    if (p < e) {
        int d0 = cdst[p]; float v0 = cval[p];
        const float* r0 = full_in ? full_in + (size_t)d0 * 64
                                  : (d0 < NU ? uin + (size_t)d0 * 64 : iin + (size_t)(d0 - NU) * 64);
        acc += v0 * r0[lane];
    }
    out[(size_t)row * 64 + lane] = acc;
}

// ---------- 8. final ----------

__global__ __launch_bounds__(256) void final_out(const float* __restrict__ ue, const float* __restrict__ ie,
                                                 const float* __restrict__ e1, const float* __restrict__ e2,
                                                 const float* __restrict__ hnorm, float* __restrict__ out) {
    int g = blockIdx.x * 256 + threadIdx.x;
    if (g >= NNODE * 16) return;
    int n = g >> 4;
    float4 a = (n < NU) ? ((const float4*)ue)[g] : ((const float4*)ie)[g - NU * 16];
    float4 b = ((const float4*)e1)[g];
    float4 c = ((const float4*)e2)[g];
    const float third = 1.0f / 3.0f;
    float4 r;
    r.x = (a.x + b.x + c.x) * third;
    r.y = (a.y + b.y + c.y) * third;
    r.z = (a.z + b.z + c.z) * third;
    r.w = (a.w + b.w + c.w) * third;
    if (n >= NU) {
        float4 h = ((const float4*)hnorm)[g - NU * 16];
        r.x += h.x; r.y += h.y; r.z += h.z; r.w += h.w;
    }
    ((float4*)out)[g] = r;
}

// ---------- launch ----------

extern "C" void kernel_launch(void* const* d_in, const int* in_sizes, int n_in,
                              void* d_out, int out_size, void* d_ws, size_t ws_size,
                              hipStream_t stream) {
    const float* user_emb   = (const float*)d_in[0];
    const float* item_emb   = (const float*)d_in[1];
    const float* image_feat = (const float*)d_in[2];
    const float* text_feat  = (const float*)d_in[3];
    const float* img_w      = (const float*)d_in[4];
    const float* img_b      = (const float*)d_in[5];
    const float* txt_w      = (const float*)d_in[6];
    const float* txt_b      = (const float*)d_in[7];
    const float* mw         = (const float*)d_in[8];
    const float* img_orig   = (const float*)d_in[9];
    const float* txt_orig   = (const float*)d_in[10];
    const int*   aidx       = (const int*)d_in[11];
    const float* avals      = (const float*)d_in[12];

    // workspace layout (float elements)
    float* C_img = (float*)d_ws;
    float* C_txt = C_img + (size_t)NI * EMB;
    unsigned short* xh_img = (unsigned short*)(C_txt + (size_t)NI * EMB);
    unsigned short* xl_img = xh_img + (size_t)NI * EMB;
    unsigned short* xh_txt = xl_img + (size_t)NI * EMB;
    unsigned short* xl_txt = xh_txt + (size_t)NI * EMB;
    float* tkvA    = (float*)(xl_txt + (size_t)NI * EMB);        // 2*NI*NCH*10
    float* tau     = tkvA + (size_t)2 * NI * NCH * 10;           // 2*NI
    int*   ccnt    = (int*)(tau + 2 * NI);                       // 2*NI
    float* candv   = (float*)(ccnt + 2 * NI);                    // 2*NI*MAXC
    int*   candc   = (int*)(candv + (size_t)2 * NI * MAXC);      // 2*NI*MAXC
    float* fin_val = (float*)(candc + (size_t)2 * NI * MAXC);    // 2*NI*10
    int*   fin_idx = (int*)(fin_val + 2 * NI * 10);              // 2*NI*10
    float* dinv    = (float*)(fin_idx + 2 * NI * 10);
    float* hnorm   = dinv + NI;
    float* ego1    = hnorm + (size_t)NI * EMB;
    float* ego2    = ego1 + (size_t)NNODE * EMB;
    int* cnt      = (int*)(ego2 + (size_t)NNODE * EMB);
    int* row_ptr  = cnt + NNODE;
    int* fill     = row_ptr + NNODE + 1;
    int* partials = fill + NNODE;
    int* csr_dst  = partials + 128;
    float* csr_val = (float*)(csr_dst + NNZE);

    hipMemsetAsync(C_img, 0, (size_t)NI * EMB * 4, stream);
    hipMemsetAsync(C_txt, 0, (size_t)NI * EMB * 4, stream);
    hipMemsetAsync(cnt, 0, (size_t)NNODE * 4, stream);
    hipMemsetAsync(ccnt, 0, (size_t)2 * NI * 4, stream);

    // CSR build (independent of everything else)
    hist_k<<<(NNZE + 255) / 256, 256, 0, stream>>>(aidx, cnt);
    scan_partial<<<NNODE / 256, 256, 0, stream>>>(cnt, row_ptr, partials);
    scan_totals<<<1, 64, 0, stream>>>(partials, row_ptr);
    add_off<<<NNODE / 256, 256, 0, stream>>>(row_ptr, partials, fill);
    scatter_k<<<(NNZE + 255) / 256, 256, 0, stream>>>(aidx, avals, fill, csr_dst, csr_val);

    // transforms
    gemm_tr<<<dim3(NI / 64, 8), 256, 0, stream>>>(image_feat, img_w, C_img, NI, VD, VD / 8);
    gemm_tr<<<dim3(NI / 64, 6), 256, 0, stream>>>(text_feat,  txt_w, C_txt, NI, TD, TD / 6);

    // normalize + bf16 split
    rownorm<<<NI / 4, 256, 0, stream>>>(C_img, img_b, xh_img, xl_img);
    rownorm<<<NI / 4, 256, 0, stream>>>(C_txt, txt_b, xh_txt, xl_txt);

    // Pass A: per-chunk top-10 values
    sims_tauA<<<dim3(NI / 64, NCH, 2), 256, 0, stream>>>(xh_img, xl_img, xh_txt, xl_txt, tkvA);
    // exact per-row 10th-largest
    tau_merge<<<(2 * NI + 255) / 256, 256, 0, stream>>>(tkvA, tau);
    // Pass B: recompute + collect candidates >= tau
    sims_collect<<<dim3(NI / 64, NCH, 2), 256, 0, stream>>>(xh_img, xl_img, xh_txt, xl_txt,
                                                            tau, ccnt, candv, candc);
    // final exact top-10 with lax.top_k tie-breaking
    topk_cand<<<(2 * NI + 255) / 256, 256, 0, stream>>>(ccnt, candv, candc, fin_val, fin_idx);

    // degrees
    calc_dinv<<<(NI + 255) / 256, 256, 0, stream>>>(fin_val, mw, dinv);

    // h + normalize
    compute_h<<<NI, 256, 0, stream>>>(img_orig, txt_orig, item_emb, fin_val, fin_idx, dinv, mw, hnorm);

    // two propagation layers via CSR gather
    ui_gather<<<NNODE / 4, 256, 0, stream>>>(user_emb, item_emb, nullptr, row_ptr, csr_dst, csr_val, ego1);
    ui_gather<<<NNODE / 4, 256, 0, stream>>>(user_emb, item_emb, ego1,    row_ptr, csr_dst, csr_val, ego2);

    // final output
    final_out<<<(NNODE * 16 + 255) / 256, 256, 0, stream>>>(user_emb, item_emb, ego1, ego2, hnorm, (float*)d_out);
}

// Round 8
// 984.475 us; speedup vs baseline: 2.1573x; 1.0505x over previous
//
#include <hip/hip_runtime.h>
#include <hip/hip_bf16.h>

#define NU 19968
#define NI 6144
#define NNODE (NU + NI)
#define EMB 64
#define VD 4096
#define TD 384
#define NNZE 600000
#define LAMB 0.9f
#define NCH 16
#define CPC (NI / NCH)   // 384 cols per chunk
#define MAXC 16          // candidate cap per row

typedef __attribute__((ext_vector_type(8))) short bf16x8;
typedef __attribute__((ext_vector_type(4))) float f32x4;
#define MFMA16(a, b, c) __builtin_amdgcn_mfma_f32_16x16x32_bf16(a, b, c, 0, 0, 0)

// ---------- helpers ----------

// values-only sorted-insert: 2 ops/step, no branches inside
__device__ __forceinline__ void vins(float (&cv)[10], float v) {
#pragma unroll
    for (int s = 0; s < 10; ++s) {
        float mx = fmaxf(cv[s], v);
        v = fminf(cv[s], v);
        cv[s] = mx;
    }
}

// (value desc, col asc) tie-break insert — matches lax.top_k stability
__device__ __forceinline__ void topk_ins_tie(float (&cv)[10], int (&ci)[10], float v, int j) {
#pragma unroll
    for (int s = 0; s < 10; ++s) {
        bool take = (v > cv[s]) || (v == cv[s] && j < ci[s]);
        if (take) {
            float tv = cv[s]; cv[s] = v; v = tv;
            int tj = ci[s]; ci[s] = j; j = tj;
        }
    }
}

__device__ __forceinline__ float2 softmax2(const float* mw) {
    float e0 = expf(mw[0]), e1 = expf(mw[1]);
    float inv = 1.0f / (e0 + e1);
    return make_float2(e0 * inv, e1 * inv);
}

__device__ __forceinline__ unsigned short f2bf(float f) {      // RNE f32->bf16 bits
    unsigned int u = __float_as_uint(f);
    unsigned int r = (u + 0x7FFFu + ((u >> 16) & 1u)) >> 16;
    return (unsigned short)r;
}
__device__ __forceinline__ float bf2f(unsigned short h) { return __uint_as_float(((unsigned int)h) << 16); }

// shared sim-tile evaluator — MUST be bit-identical between pass A and pass B:
// the 6-MFMA chain is dependency-ordered so results are deterministic.
__device__ __forceinline__ f32x4 sim_tile(const unsigned short* __restrict__ xh,
                                          const unsigned short* __restrict__ xl,
                                          bf16x8 ahi0, bf16x8 ahi1, bf16x8 alo0, bf16x8 alo1,
                                          int c, int fq) {
    const size_t bbase = (size_t)c * 64 + fq * 8;
    bf16x8 bhi0 = *(const bf16x8*)(xh + bbase);
    bf16x8 bhi1 = *(const bf16x8*)(xh + bbase + 32);
    bf16x8 blo0 = *(const bf16x8*)(xl + bbase);
    bf16x8 blo1 = *(const bf16x8*)(xl + bbase + 32);
    f32x4 a = {0.f, 0.f, 0.f, 0.f};
    a = MFMA16(ahi0, bhi0, a);
    a = MFMA16(ahi1, bhi1, a);
    a = MFMA16(ahi0, blo0, a);
    a = MFMA16(ahi1, blo1, a);
    a = MFMA16(alo0, bhi0, a);
    a = MFMA16(alo1, bhi1, a);
    return a;
}

// ---------- 1. transform GEMM via split-bf16 MFMA ----------
// Cp[slab][NI][64] = A[:, slab*kps : (slab+1)*kps] @ W[slab-range][64]
// 64-row x 64-col tile per block, K-64 inner steps, f32->bf16 hi/lo split in LDS staging.

__global__ __launch_bounds__(256) void gemm_mfma(const float* __restrict__ A, const float* __restrict__ W,
                                                 float* __restrict__ Cp, int K, int kps) {
    __shared__ unsigned short Ah[64][72], Al[64][72], Wh[64][72], Wl[64][72];
    const int t = threadIdx.x;
    const int m0 = blockIdx.x * 64;
    const int k0 = blockIdx.y * kps;
    const int wv = t >> 6, lane = t & 63;
    const int fr = lane & 15, fq = lane >> 4;
    f32x4 acc[4] = {{0,0,0,0},{0,0,0,0},{0,0,0,0},{0,0,0,0}};
    for (int kt = k0; kt < k0 + kps; kt += 64) {
        __syncthreads();
        // stage A 64x64 (f32 -> hi/lo bf16), layout [m][k]
#pragma unroll
        for (int q = 0; q < 4; ++q) {
            int i = t + 256 * q;
            int m = i >> 4, k4 = (i & 15) << 2;
            float4 v = *(const float4*)(A + (size_t)(m0 + m) * K + kt + k4);
            float f[4] = {v.x, v.y, v.z, v.w};
#pragma unroll
            for (int j = 0; j < 4; ++j) {
                unsigned short h = f2bf(f[j]);
                Ah[m][k4 + j] = h;
                Al[m][k4 + j] = f2bf(f[j] - bf2f(h));
            }
        }
        // stage W 64x64 transposed to [n][k]
#pragma unroll
        for (int q = 0; q < 4; ++q) {
            int i = t + 256 * q;
            int kk = i >> 4, n4 = (i & 15) << 2;
            float4 v = *(const float4*)(W + (size_t)(kt + kk) * 64 + n4);
            float f[4] = {v.x, v.y, v.z, v.w};
#pragma unroll
            for (int j = 0; j < 4; ++j) {
                unsigned short h = f2bf(f[j]);
                Wh[n4 + j][kk] = h;
                Wl[n4 + j][kk] = f2bf(f[j] - bf2f(h));
            }
        }
        __syncthreads();
#pragma unroll
        for (int k2 = 0; k2 < 2; ++k2) {
            bf16x8 ah = *(const bf16x8*)&Ah[wv * 16 + fr][k2 * 32 + fq * 8];
            bf16x8 al = *(const bf16x8*)&Al[wv * 16 + fr][k2 * 32 + fq * 8];
#pragma unroll
            for (int cs = 0; cs < 4; ++cs) {
                bf16x8 wh = *(const bf16x8*)&Wh[cs * 16 + fr][k2 * 32 + fq * 8];
                bf16x8 wl = *(const bf16x8*)&Wl[cs * 16 + fr][k2 * 32 + fq * 8];
                acc[cs] = MFMA16(ah, wh, acc[cs]);
                acc[cs] = MFMA16(ah, wl, acc[cs]);
                acc[cs] = MFMA16(al, wh, acc[cs]);
            }
        }
    }
    const size_t base = (size_t)blockIdx.y * NI * 64;
#pragma unroll
    for (int cs = 0; cs < 4; ++cs)
#pragma unroll
        for (int r = 0; r < 4; ++r)
            Cp[base + (size_t)(m0 + wv * 16 + fq * 4 + r) * 64 + cs * 16 + fr] = acc[cs][r];
}

// ---------- 2. sum slabs + bias + row-normalize -> split bf16 (hi, lo) ----------

__global__ __launch_bounds__(256) void rownorm(const float* __restrict__ Cp, const float* __restrict__ bias,
                                               unsigned short* __restrict__ xh, unsigned short* __restrict__ xl,
                                               int ns) {
    int row = blockIdx.x * 4 + (threadIdx.x >> 6);
    int lane = threadIdx.x & 63;
    float v = 0.f;
    for (int s = 0; s < ns; ++s) v += Cp[((size_t)s * NI + row) * 64 + lane];
    v += bias[lane];
    float ss = v * v;
#pragma unroll
    for (int o = 32; o; o >>= 1) ss += __shfl_xor(ss, o, 64);
    float xn = v * (1.0f / sqrtf(ss));
    unsigned short h = f2bf(xn);
    float lo = xn - bf2f(h);
    xh[(size_t)row * 64 + lane] = h;
    xl[(size_t)row * 64 + lane] = f2bf(lo);
}

// ---------- 3a. Pass A: per-(row,chunk) top-10 VALUES (no indices) ----------

__global__ __launch_bounds__(256) void sims_tauA(const unsigned short* __restrict__ xh_img,
                                                 const unsigned short* __restrict__ xl_img,
                                                 const unsigned short* __restrict__ xh_txt,
                                                 const unsigned short* __restrict__ xl_txt,
                                                 float* __restrict__ tkv) {
    const unsigned short* xh = blockIdx.z ? xh_txt : xh_img;
    const unsigned short* xl = blockIdx.z ? xl_txt : xl_img;
    const int r0 = blockIdx.x * 64;
    const int c0 = blockIdx.y * CPC;
    const int t = threadIdx.x;
    const int wave = t >> 6, lane = t & 63;
    const int fr = lane & 15, fq = lane >> 4;

    const size_t abase = (size_t)(r0 + wave * 16 + fr) * 64 + fq * 8;
    bf16x8 ahi0 = *(const bf16x8*)(xh + abase);
    bf16x8 ahi1 = *(const bf16x8*)(xh + abase + 32);
    bf16x8 alo0 = *(const bf16x8*)(xl + abase);
    bf16x8 alo1 = *(const bf16x8*)(xl + abase + 32);

    float cv[4][10];
#pragma unroll
    for (int r = 0; r < 4; ++r)
#pragma unroll
        for (int s = 0; s < 10; ++s) cv[r][s] = -INFINITY;

    for (int ct = 0; ct < CPC / 64; ++ct) {
        const int cbase = c0 + ct * 64;
#pragma unroll
        for (int cs = 0; cs < 4; ++cs) {
            f32x4 a = sim_tile(xh, xl, ahi0, ahi1, alo0, alo1, cbase + cs * 16 + fr, fq);
#pragma unroll
            for (int r = 0; r < 4; ++r)
                if (a[r] > cv[r][9]) vins(cv[r], a[r]);
        }
    }

    // butterfly merge of the 16 lane-lists per row
#pragma unroll
    for (int m = 1; m <= 8; m <<= 1) {
#pragma unroll
        for (int r = 0; r < 4; ++r) {
            float ov[10];
#pragma unroll
            for (int s = 0; s < 10; ++s) ov[s] = __shfl_xor(cv[r][s], m);
            bool done = false;
#pragma unroll
            for (int s = 0; s < 10; ++s) {
                if (!done) {
                    if (__all(ov[s] <= cv[r][9])) done = true;
                    else if (ov[s] > cv[r][9]) vins(cv[r], ov[s]);
                }
            }
        }
    }

    if (fr == 0) {
#pragma unroll
        for (int r = 0; r < 4; ++r) {
            int row = r0 + wave * 16 + fq * 4 + r;
            size_t base = ((size_t)(blockIdx.z * NI + row) * NCH + blockIdx.y) * 10;
#pragma unroll
            for (int s = 0; s < 10; ++s) tkv[base + s] = cv[r][s];
        }
    }
}

// ---------- 3b. merge chunk value-lists -> exact per-row 10th-largest (tau) ----------

__global__ void tau_merge(const float* __restrict__ tkv, float* __restrict__ tau) {
    int g = blockIdx.x * blockDim.x + threadIdx.x;
    if (g >= 2 * NI) return;
    float cv[10];
#pragma unroll
    for (int s = 0; s < 10; ++s) cv[s] = -INFINITY;
    for (int u = 0; u < NCH * 10; ++u) {
        float v = tkv[(size_t)g * NCH * 10 + u];
        if (v > cv[9]) vins(cv, v);
    }
    tau[g] = cv[9];
}

// ---------- 3c. Pass B: recompute sims, collect cols with v >= tau ----------

__global__ __launch_bounds__(256) void sims_collect(const unsigned short* __restrict__ xh_img,
                                                    const unsigned short* __restrict__ xl_img,
                                                    const unsigned short* __restrict__ xh_txt,
                                                    const unsigned short* __restrict__ xl_txt,
                                                    const float* __restrict__ tau,
                                                    int* __restrict__ ccnt,
                                                    float* __restrict__ cval, int* __restrict__ ccol) {
    const unsigned short* xh = blockIdx.z ? xh_txt : xh_img;
    const unsigned short* xl = blockIdx.z ? xl_txt : xl_img;
    const int r0 = blockIdx.x * 64;
    const int c0 = blockIdx.y * CPC;
    const int t = threadIdx.x;
    const int wave = t >> 6, lane = t & 63;
    const int fr = lane & 15, fq = lane >> 4;

    const size_t abase = (size_t)(r0 + wave * 16 + fr) * 64 + fq * 8;
    bf16x8 ahi0 = *(const bf16x8*)(xh + abase);
    bf16x8 ahi1 = *(const bf16x8*)(xh + abase + 32);
    bf16x8 alo0 = *(const bf16x8*)(xl + abase);
    bf16x8 alo1 = *(const bf16x8*)(xl + abase + 32);

    float tv[4];
    int grow[4];
#pragma unroll
    for (int r = 0; r < 4; ++r) {
        grow[r] = blockIdx.z * NI + r0 + wave * 16 + fq * 4 + r;
        tv[r] = tau[grow[r]];
    }

    for (int ct = 0; ct < CPC / 64; ++ct) {
        const int cbase = c0 + ct * 64;
#pragma unroll
        for (int cs = 0; cs < 4; ++cs) {
            const int c = cbase + cs * 16 + fr;
            f32x4 a = sim_tile(xh, xl, ahi0, ahi1, alo0, alo1, c, fq);
#pragma unroll
            for (int r = 0; r < 4; ++r) {
                if (a[r] >= tv[r]) {
                    int p = atomicAdd(&ccnt[grow[r]], 1);
                    if (p < MAXC) {
                        cval[(size_t)grow[r] * MAXC + p] = a[r];
                        ccol[(size_t)grow[r] * MAXC + p] = c;
                    }
                }
            }
        }
    }
}

// ---------- 3d. final exact top-10 from candidates (tie-break = lowest col) ----------

__global__ void topk_cand(const int* __restrict__ ccnt, const float* __restrict__ cval,
                          const int* __restrict__ ccol,
                          float* __restrict__ fvv, int* __restrict__ fii) {
    int g = blockIdx.x * blockDim.x + threadIdx.x;
    if (g >= 2 * NI) return;
    float cv[10]; int ci[10];
#pragma unroll
    for (int s = 0; s < 10; ++s) { cv[s] = -INFINITY; ci[s] = 0x7fffffff; }
    int n = ccnt[g]; if (n > MAXC) n = MAXC;
    for (int u = 0; u < n; ++u)
        topk_ins_tie(cv, ci, cval[(size_t)g * MAXC + u], ccol[(size_t)g * MAXC + u]);
#pragma unroll
    for (int s = 0; s < 10; ++s) { fvv[(size_t)g * 10 + s] = cv[s]; fii[(size_t)g * 10 + s] = ci[s]; }
}

// ---------- 4. degree^-1/2 ----------

__global__ void calc_dinv(const float* __restrict__ fvv, const float* __restrict__ mw, float* __restrict__ dinv) {
    int i = blockIdx.x * blockDim.x + threadIdx.x;
    if (i >= NI) return;
    float2 w = softmax2(mw);
    float s = 0.f;
    for (int u = 0; u < 10; ++u) s += w.x * fvv[(size_t)i * 10 + u];
    for (int u = 0; u < 10; ++u) s += w.y * fvv[(size_t)(NI + i) * 10 + u];
    dinv[i] = (s > 0.f) ? (1.0f / sqrtf(s)) : 0.f;
}

// ---------- 5. h = item_adj @ item_emb, row-normalize ----------

__global__ __launch_bounds__(256) void compute_h(const float* __restrict__ img_o, const float* __restrict__ txt_o,
                                                 const float* __restrict__ item_emb,
                                                 const float* __restrict__ fvv, const int* __restrict__ fii,
                                                 const float* __restrict__ dinv, const float* __restrict__ mw,
                                                 float* __restrict__ hnorm) {
    const int i = blockIdx.x;
    const int t = threadIdx.x;
    __shared__ int   sj[64];
    __shared__ float sc[64];
    __shared__ int   scnt;
    __shared__ float part[4][64];
    if (t == 0) scnt = 0;
    __syncthreads();
    float2 w = softmax2(mw);
    const float4* ro = (const float4*)(img_o + (size_t)i * NI);
    const float4* to = (const float4*)(txt_o + (size_t)i * NI);
    for (int u = t; u < NI / 4; u += 256) {
        float4 a = ro[u], b = to[u];
        float c[4] = { w.x * a.x + w.y * b.x, w.x * a.y + w.y * b.y,
                       w.x * a.z + w.y * b.z, w.x * a.w + w.y * b.w };
#pragma unroll
        for (int q = 0; q < 4; ++q)
            if (c[q] != 0.f) { int p = atomicAdd(&scnt, 1); sj[p] = u * 4 + q; sc[p] = LAMB * c[q]; }
    }
    if (t < 20) {
        int m = t / 10, s = t % 10;
        float v = fvv[((size_t)m * NI + i) * 10 + s];
        int   j = fii[((size_t)m * NI + i) * 10 + s];
        float wm = m ? w.y : w.x;
        float c = (1.0f - LAMB) * wm * v * dinv[i] * dinv[j];
        int p = atomicAdd(&scnt, 1); sj[p] = j; sc[p] = c;
    }
    __syncthreads();
    const int cnt = scnt;
    const int dim = t & 63, q = t >> 6;
    float acc = 0.f;
    for (int e = q; e < cnt; e += 4) acc += sc[e] * item_emb[(size_t)sj[e] * 64 + dim];
    part[q][dim] = acc;
    __syncthreads();
    if (t < 64) {
        float h = part[0][t] + part[1][t] + part[2][t] + part[3][t];
        float ss = h * h;
#pragma unroll
        for (int o = 32; o; o >>= 1) ss += __shfl_xor(ss, o, 64);
        float scale = 1.0f / fmaxf(sqrtf(ss), 1e-12f);
        hnorm[(size_t)i * 64 + t] = h * scale;
    }
}

// ---------- 6. CSR build ----------

__global__ void hist_k(const int* __restrict__ aidx, int* __restrict__ cnt) {
    int e = blockIdx.x * 256 + threadIdx.x;
    if (e < NNZE) atomicAdd(&cnt[aidx[e]], 1);
}

__global__ void scan_partial(const int* __restrict__ cnt, int* __restrict__ rp, int* __restrict__ partials) {
    __shared__ int sm[256];
    int t = threadIdx.x;
    int i = blockIdx.x * 256 + t;
    int v = cnt[i];
    sm[t] = v;
    __syncthreads();
    for (int o = 1; o < 256; o <<= 1) {
        int x = (t >= o) ? sm[t - o] : 0;
        __syncthreads();
        sm[t] += x;
        __syncthreads();
    }
    rp[i] = sm[t] - v;                    // exclusive within block
    if (t == 255) partials[blockIdx.x] = sm[255];
}

// parallel scan over the 102 block partials (one 128-thread block)
__global__ void scan_totals(int* __restrict__ partials, int* __restrict__ rp) {
    __shared__ int sm[128];
    int t = threadIdx.x;
    const int NB = NNODE / 256;
    int v = (t < NB) ? partials[t] : 0;
    sm[t] = v;
    __syncthreads();
    for (int o = 1; o < 128; o <<= 1) {
        int x = (t >= o) ? sm[t - o] : 0;
        __syncthreads();
        sm[t] += x;
        __syncthreads();
    }
    if (t < NB) partials[t] = sm[t] - v;   // exclusive
    if (t == 127) rp[NNODE] = sm[127];
}

__global__ void add_off(int* __restrict__ rp, const int* __restrict__ partials, int* __restrict__ fill) {
    int i = blockIdx.x * 256 + threadIdx.x;
    int v = rp[i] + partials[blockIdx.x];
    rp[i] = v;
    fill[i] = v;
}

__global__ void scatter_k(const int* __restrict__ aidx, const float* __restrict__ avals,
                          int* __restrict__ fill, int* __restrict__ cdst, float* __restrict__ cval) {
    int e = blockIdx.x * 256 + threadIdx.x;
    if (e >= NNZE) return;
    int src = aidx[e];
    int p = atomicAdd(&fill[src], 1);
    cdst[p] = aidx[NNZE + e];
    cval[p] = avals[e];
}

// ---------- 7. gather propagation: 1 wave/row, 4 edges in flight ----------
// lane = (egrp = lane>>4) edge-slot x (g16 = lane&15) float4-dim-slot

__global__ __launch_bounds__(256) void ui_gather(const float* __restrict__ uin, const float* __restrict__ iin,
                                                 const float* __restrict__ full_in,
                                                 const int* __restrict__ rp, const int* __restrict__ cdst,
                                                 const float* __restrict__ cval, float* __restrict__ out) {
    int row = blockIdx.x * 4 + (threadIdx.x >> 6);
    int lane = threadIdx.x & 63;
    int g16 = lane & 15, egrp = lane >> 4;
    int s = rp[row], e = rp[row + 1];
    float4 acc = {0.f, 0.f, 0.f, 0.f};
    for (int p = s + egrp; p < e; p += 4) {
        int d = cdst[p];
        float v = cval[p];
        const float* r0 = full_in ? full_in + (size_t)d * 64
                                  : (d < NU ? uin + (size_t)d * 64 : iin + (size_t)(d - NU) * 64);
        float4 x = *(const float4*)(r0 + g16 * 4);
        acc.x += v * x.x; acc.y += v * x.y; acc.z += v * x.z; acc.w += v * x.w;
    }
#pragma unroll
    for (int m = 16; m <= 32; m <<= 1) {
        acc.x += __shfl_xor(acc.x, m, 64);
        acc.y += __shfl_xor(acc.y, m, 64);
        acc.z += __shfl_xor(acc.z, m, 64);
        acc.w += __shfl_xor(acc.w, m, 64);
    }
    if (egrp == 0) *(float4*)(out + (size_t)row * 64 + g16 * 4) = acc;
}

// ---------- 8. final ----------

__global__ __launch_bounds__(256) void final_out(const float* __restrict__ ue, const float* __restrict__ ie,
                                                 const float* __restrict__ e1, const float* __restrict__ e2,
                                                 const float* __restrict__ hnorm, float* __restrict__ out) {
    int g = blockIdx.x * 256 + threadIdx.x;
    if (g >= NNODE * 16) return;
    int n = g >> 4;
    float4 a = (n < NU) ? ((const float4*)ue)[g] : ((const float4*)ie)[g - NU * 16];
    float4 b = ((const float4*)e1)[g];
    float4 c = ((const float4*)e2)[g];
    const float third = 1.0f / 3.0f;
    float4 r;
    r.x = (a.x + b.x + c.x) * third;
    r.y = (a.y + b.y + c.y) * third;
    r.z = (a.z + b.z + c.z) * third;
    r.w = (a.w + b.w + c.w) * third;
    if (n >= NU) {
        float4 h = ((const float4*)hnorm)[g - NU * 16];
        r.x += h.x; r.y += h.y; r.z += h.z; r.w += h.w;
    }
    ((float4*)out)[g] = r;
}

// ---------- launch ----------

extern "C" void kernel_launch(void* const* d_in, const int* in_sizes, int n_in,
                              void* d_out, int out_size, void* d_ws, size_t ws_size,
                              hipStream_t stream) {
    const float* user_emb   = (const float*)d_in[0];
    const float* item_emb   = (const float*)d_in[1];
    const float* image_feat = (const float*)d_in[2];
    const float* text_feat  = (const float*)d_in[3];
    const float* img_w      = (const float*)d_in[4];
    const float* img_b      = (const float*)d_in[5];
    const float* txt_w      = (const float*)d_in[6];
    const float* txt_b      = (const float*)d_in[7];
    const float* mw         = (const float*)d_in[8];
    const float* img_orig   = (const float*)d_in[9];
    const float* txt_orig   = (const float*)d_in[10];
    const int*   aidx       = (const int*)d_in[11];
    const float* avals      = (const float*)d_in[12];

    // ---- workspace layout (float elements) ----
    // Union region R (7,471,104 floats):
    //   phase 1 (GEMM+sims): Cp_img[8*NI*64]=3,145,728 | Cp_txt[6*NI*64]=2,359,296 | tkvA[2*NI*NCH*10]=1,966,080
    //   phase 2 (propagation, after tau_merge): ego1[NNODE*64]=1,671,168 | ego2[1,671,168] (fits in first 3.35M)
    float* R = (float*)d_ws;
    float* Cp_img = R;
    float* Cp_txt = R + 3145728;
    float* tkvA   = R + 3145728 + 2359296;
    float* ego1   = R;                       // aliases Cp_img (dead after rownorm)
    float* ego2   = R + 1671168;             // aliases Cp_img/Cp_txt tail (dead after rownorm)

    float* after = R + 7471104;
    unsigned short* xh_img = (unsigned short*)after;             // 4 x NI*64 ushort
    unsigned short* xl_img = xh_img + (size_t)NI * EMB;
    unsigned short* xh_txt = xl_img + (size_t)NI * EMB;
    unsigned short* xl_txt = xh_txt + (size_t)NI * EMB;
    float* tau     = (float*)(xl_txt + (size_t)NI * EMB);        // 2*NI
    int*   ccnt    = (int*)(tau + 2 * NI);                       // 2*NI
    float* candv   = (float*)(ccnt + 2 * NI);                    // 2*NI*MAXC
    int*   candc   = (int*)(candv + (size_t)2 * NI * MAXC);      // 2*NI*MAXC
    float* fin_val = (float*)(candc + (size_t)2 * NI * MAXC);    // 2*NI*10
    int*   fin_idx = (int*)(fin_val + 2 * NI * 10);              // 2*NI*10
    float* dinv    = (float*)(fin_idx + 2 * NI * 10);
    float* hnorm   = dinv + NI;
    int* cnt      = (int*)(hnorm + (size_t)NI * EMB);
    int* row_ptr  = cnt + NNODE;
    int* fill     = row_ptr + NNODE + 1;
    int* partials = fill + NNODE;
    int* csr_dst  = partials + 128;
    float* csr_val = (float*)(csr_dst + NNZE);

    hipMemsetAsync(cnt, 0, (size_t)NNODE * 4, stream);
    hipMemsetAsync(ccnt, 0, (size_t)2 * NI * 4, stream);

    // CSR build (independent of everything else)
    hist_k<<<(NNZE + 255) / 256, 256, 0, stream>>>(aidx, cnt);
    scan_partial<<<NNODE / 256, 256, 0, stream>>>(cnt, row_ptr, partials);
    scan_totals<<<1, 128, 0, stream>>>(partials, row_ptr);
    add_off<<<NNODE / 256, 256, 0, stream>>>(row_ptr, partials, fill);
    scatter_k<<<(NNZE + 255) / 256, 256, 0, stream>>>(aidx, avals, fill, csr_dst, csr_val);

    // transforms via MFMA (per-slab partials, no atomics)
    gemm_mfma<<<dim3(NI / 64, 8), 256, 0, stream>>>(image_feat, img_w, Cp_img, VD, VD / 8);
    gemm_mfma<<<dim3(NI / 64, 6), 256, 0, stream>>>(text_feat,  txt_w, Cp_txt, TD, TD / 6);

    // slab-sum + bias + normalize + bf16 split
    rownorm<<<NI / 4, 256, 0, stream>>>(Cp_img, img_b, xh_img, xl_img, 8);
    rownorm<<<NI / 4, 256, 0, stream>>>(Cp_txt, txt_b, xh_txt, xl_txt, 6);

    // Pass A: per-chunk top-10 values
    sims_tauA<<<dim3(NI / 64, NCH, 2), 256, 0, stream>>>(xh_img, xl_img, xh_txt, xl_txt, tkvA);
    // exact per-row 10th-largest
    tau_merge<<<(2 * NI + 255) / 256, 256, 0, stream>>>(tkvA, tau);
    // Pass B: recompute + collect candidates >= tau
    sims_collect<<<dim3(NI / 64, NCH, 2), 256, 0, stream>>>(xh_img, xl_img, xh_txt, xl_txt,
                                                            tau, ccnt, candv, candc);
    // final exact top-10 with lax.top_k tie-breaking
    topk_cand<<<(2 * NI + 255) / 256, 256, 0, stream>>>(ccnt, candv, candc, fin_val, fin_idx);

    // degrees
    calc_dinv<<<(NI + 255) / 256, 256, 0, stream>>>(fin_val, mw, dinv);

    // h + normalize
    compute_h<<<NI, 256, 0, stream>>>(img_orig, txt_orig, item_emb, fin_val, fin_idx, dinv, mw, hnorm);

    // two propagation layers via CSR gather (ego1/ego2 alias dead Cp region)
    ui_gather<<<NNODE / 4, 256, 0, stream>>>(user_emb, item_emb, nullptr, row_ptr, csr_dst, csr_val, ego1);
    ui_gather<<<NNODE / 4, 256, 0, stream>>>(user_emb, item_emb, ego1,    row_ptr, csr_dst, csr_val, ego2);

    // final output
    final_out<<<(NNODE * 16 + 255) / 256, 256, 0, stream>>>(user_emb, item_emb, ego1, ego2, hnorm, (float*)d_out);
}